// Round 3
// baseline (590.350 us; speedup 1.0000x reference)
//
#include <hip/hip_runtime.h>
#include <math.h>

// GATv2 2-layer: N=50000 nodes, E=600000 edges, heads=8, C1=32, C2=16.
// Pipeline: CSR build (hist/scan/scatter) -> GEMM(xl1,xr1) -> GAT1(+ELU)
//           -> GEMM(xl2,xr2) -> GAT2(+log_softmax).
constexpr int NN = 50000;
constexpr int NE = 600000;
constexpr int NB = (NN + 255) / 256;   // 196 scan blocks

// ---------------- CSR build ----------------
__global__ __launch_bounds__(256) void k_hist(const int* __restrict__ ei,
                                              int* __restrict__ deg) {
    int e = blockIdx.x * 256 + threadIdx.x;
    if (e < NE) atomicAdd(&deg[ei[NE + e]], 1);
}

__global__ __launch_bounds__(256) void k_scan_block(const int* __restrict__ deg,
                                                    int* __restrict__ rowptr,
                                                    int* __restrict__ bsum) {
    __shared__ int s[256];
    int tid = threadIdx.x;
    int i = blockIdx.x * 256 + tid;
    int v = (i < NN) ? deg[i] : 0;
    s[tid] = v;
    __syncthreads();
    #pragma unroll
    for (int off = 1; off < 256; off <<= 1) {
        int t = (tid >= off) ? s[tid - off] : 0;
        __syncthreads();
        s[tid] += t;
        __syncthreads();
    }
    if (i < NN) rowptr[i] = s[tid] - v;           // exclusive scan
    if (tid == 255) bsum[blockIdx.x] = s[255];
}

__global__ __launch_bounds__(256) void k_scan_top(int* __restrict__ bsum) {
    __shared__ int s[256];
    int tid = threadIdx.x;
    int v = (tid < NB) ? bsum[tid] : 0;
    s[tid] = v;
    __syncthreads();
    #pragma unroll
    for (int off = 1; off < 256; off <<= 1) {
        int t = (tid >= off) ? s[tid - off] : 0;
        __syncthreads();
        s[tid] += t;
        __syncthreads();
    }
    if (tid < NB) bsum[tid] = s[tid] - v;
}

__global__ __launch_bounds__(256) void k_scan_add(int* __restrict__ rowptr,
                                                  const int* __restrict__ bsum,
                                                  int* __restrict__ cursor) {
    int i = blockIdx.x * 256 + threadIdx.x;
    if (i < NN) {
        int r = rowptr[i] + bsum[blockIdx.x];
        rowptr[i] = r;
        cursor[i] = r;
    }
    if (i == 0) rowptr[NN] = NE;
}

__global__ __launch_bounds__(256) void k_scatter(const int* __restrict__ ei,
                                                 int* __restrict__ cursor,
                                                 int* __restrict__ col) {
    int e = blockIdx.x * 256 + threadIdx.x;
    if (e < NE) {
        int s = ei[e];
        int d = ei[NE + e];
        int p = atomicAdd(&cursor[d], 1);
        col[p] = s;
    }
}

// ---------------- fused dual GEMM: Yl = X@Wl, Yr = X@Wr ----------------
// X:[NN,K] row-major, W:[K,M] row-major, Y:[NN,M].
template <int K, int M>
__global__ __launch_bounds__(256) void k_gemm2(const float* __restrict__ X,
                                               const float* __restrict__ Wl,
                                               const float* __restrict__ Wr,
                                               float* __restrict__ Yl,
                                               float* __restrict__ Yr) {
    constexpr int COMB = 2 * M;        // combined output width
    constexpr int CG = COMB / 8;       // col-groups of 8
    constexpr int TR = 256 / CG;       // thread-rows
    constexpr int RPT = 4;             // rows per thread
    constexpr int BR = TR * RPT;       // rows per block (16 or 32)
    __shared__ __align__(16) float xs[BR][K];

    int tid = threadIdx.x;
    int row0 = blockIdx.x * BR;

    constexpr int V4 = BR * K / 4;
    for (int i = tid; i < V4; i += 256) {
        int r = (i * 4) / K, c = (i * 4) % K;
        int gr = row0 + r;
        float4 v = make_float4(0.f, 0.f, 0.f, 0.f);
        if (gr < NN) v = *(const float4*)(X + (size_t)gr * K + c);
        *(float4*)&xs[r][c] = v;
    }
    __syncthreads();

    int cg = tid % CG, trow = tid / CG;
    int col0 = cg * 8;
    const float* W = (col0 < M) ? Wl : Wr;
    float* Y = (col0 < M) ? Yl : Yr;
    int c0 = (col0 < M) ? col0 : (col0 - M);
    int r0 = trow * RPT;

    float acc[RPT][8];
    #pragma unroll
    for (int r = 0; r < RPT; ++r)
        #pragma unroll
        for (int j = 0; j < 8; ++j) acc[r][j] = 0.f;

    for (int k = 0; k < K; ++k) {
        float4 w0 = *(const float4*)(W + (size_t)k * M + c0);
        float4 w1 = *(const float4*)(W + (size_t)k * M + c0 + 4);
        #pragma unroll
        for (int r = 0; r < RPT; ++r) {
            float xv = xs[r0 + r][k];
            acc[r][0] = fmaf(xv, w0.x, acc[r][0]);
            acc[r][1] = fmaf(xv, w0.y, acc[r][1]);
            acc[r][2] = fmaf(xv, w0.z, acc[r][2]);
            acc[r][3] = fmaf(xv, w0.w, acc[r][3]);
            acc[r][4] = fmaf(xv, w1.x, acc[r][4]);
            acc[r][5] = fmaf(xv, w1.y, acc[r][5]);
            acc[r][6] = fmaf(xv, w1.z, acc[r][6]);
            acc[r][7] = fmaf(xv, w1.w, acc[r][7]);
        }
    }

    #pragma unroll
    for (int r = 0; r < RPT; ++r) {
        int gr = row0 + r0 + r;
        if (gr < NN) {
            *(float4*)(Y + (size_t)gr * M + c0) =
                make_float4(acc[r][0], acc[r][1], acc[r][2], acc[r][3]);
            *(float4*)(Y + (size_t)gr * M + c0 + 4) =
                make_float4(acc[r][4], acc[r][5], acc[r][6], acc[r][7]);
        }
    }
}

// ---------------- GAT layer 1: one wave per dst node, online softmax ----------------
// 64 lanes x float4 = 256 feats; head = lane>>3 (32 feats = 8 lanes/head).
__global__ __launch_bounds__(256) void k_gat1(const float* __restrict__ xl,
                                              const float* __restrict__ xr,
                                              const float* __restrict__ att,
                                              const float* __restrict__ bias,
                                              const int* __restrict__ rowptr,
                                              const int* __restrict__ col,
                                              float* __restrict__ hout) {
    int wv = blockIdx.x * 4 + (threadIdx.x >> 6);
    if (wv >= NN) return;
    int lane = threadIdx.x & 63;
    int c0 = lane * 4;

    float4 xr4 = *(const float4*)(xr + (size_t)wv * 256 + c0);
    float4 a4 = *(const float4*)(att + c0);
    float4 acc = make_float4(0.f, 0.f, 0.f, 0.f);
    float mrun = -1e30f, lrun = 0.f;

    int beg = rowptr[wv], end = rowptr[wv + 1];
    for (int idx = beg; idx <= end; ++idx) {         // <= : implicit self loop
        int src = (idx < end) ? col[idx] : wv;
        float4 m4 = *(const float4*)(xl + (size_t)src * 256 + c0);
        float sx = m4.x + xr4.x; sx = sx > 0.f ? sx : 0.2f * sx;
        float sy = m4.y + xr4.y; sy = sy > 0.f ? sy : 0.2f * sy;
        float sz = m4.z + xr4.z; sz = sz > 0.f ? sz : 0.2f * sz;
        float sw = m4.w + xr4.w; sw = sw > 0.f ? sw : 0.2f * sw;
        float p = sx * a4.x + sy * a4.y + sz * a4.z + sw * a4.w;
        p += __shfl_xor(p, 1);
        p += __shfl_xor(p, 2);
        p += __shfl_xor(p, 4);                       // logit for this head
        float nm = fmaxf(mrun, p);
        float sc = __expf(mrun - nm);
        float w = __expf(p - nm);
        acc.x = acc.x * sc + m4.x * w;
        acc.y = acc.y * sc + m4.y * w;
        acc.z = acc.z * sc + m4.z * w;
        acc.w = acc.w * sc + m4.w * w;
        lrun = lrun * sc + w;
        mrun = nm;
    }
    float inv = 1.f / lrun;
    float4 b4 = *(const float4*)(bias + c0);
    float ox = acc.x * inv + b4.x; ox = ox > 0.f ? ox : (__expf(ox) - 1.f);  // ELU
    float oy = acc.y * inv + b4.y; oy = oy > 0.f ? oy : (__expf(oy) - 1.f);
    float oz = acc.z * inv + b4.z; oz = oz > 0.f ? oz : (__expf(oz) - 1.f);
    float ow = acc.w * inv + b4.w; ow = ow > 0.f ? ow : (__expf(ow) - 1.f);
    *(float4*)(hout + (size_t)wv * 256 + c0) = make_float4(ox, oy, oz, ow);
}

// ---------------- GAT layer 2 + log_softmax ----------------
// 64 lanes x float2 = 128 feats; head = lane>>3 (16 feats = 8 lanes/head).
__global__ __launch_bounds__(256) void k_gat2(const float* __restrict__ xl,
                                              const float* __restrict__ xr,
                                              const float* __restrict__ att,
                                              const float* __restrict__ bias,
                                              const int* __restrict__ rowptr,
                                              const int* __restrict__ col,
                                              float* __restrict__ out) {
    int wv = blockIdx.x * 4 + (threadIdx.x >> 6);
    if (wv >= NN) return;
    int lane = threadIdx.x & 63;
    int c0 = lane * 2;

    float2 xr2 = *(const float2*)(xr + (size_t)wv * 128 + c0);
    float2 a2 = *(const float2*)(att + c0);
    float ax = 0.f, ay = 0.f;
    float mrun = -1e30f, lrun = 0.f;

    int beg = rowptr[wv], end = rowptr[wv + 1];
    for (int idx = beg; idx <= end; ++idx) {
        int src = (idx < end) ? col[idx] : wv;
        float2 m2 = *(const float2*)(xl + (size_t)src * 128 + c0);
        float sx = m2.x + xr2.x; sx = sx > 0.f ? sx : 0.2f * sx;
        float sy = m2.y + xr2.y; sy = sy > 0.f ? sy : 0.2f * sy;
        float p = sx * a2.x + sy * a2.y;
        p += __shfl_xor(p, 1);
        p += __shfl_xor(p, 2);
        p += __shfl_xor(p, 4);
        float nm = fmaxf(mrun, p);
        float sc = __expf(mrun - nm);
        float w = __expf(p - nm);
        ax = ax * sc + m2.x * w;
        ay = ay * sc + m2.y * w;
        lrun = lrun * sc + w;
        mrun = nm;
    }
    float inv = 1.f / lrun;
    float ox = ax * inv + bias[c0];
    float oy = ay * inv + bias[c0 + 1];

    // log_softmax over all 128 values of this node (2 per lane, 64 lanes)
    float mx = fmaxf(ox, oy);
    #pragma unroll
    for (int off = 1; off < 64; off <<= 1) mx = fmaxf(mx, __shfl_xor(mx, off));
    float se = __expf(ox - mx) + __expf(oy - mx);
    #pragma unroll
    for (int off = 1; off < 64; off <<= 1) se += __shfl_xor(se, off);
    float lse = mx + logf(se);

    out[(size_t)wv * 128 + c0] = ox - lse;
    out[(size_t)wv * 128 + c0 + 1] = oy - lse;
}

// ---------------- launch ----------------
extern "C" void kernel_launch(void* const* d_in, const int* in_sizes, int n_in,
                              void* d_out, int out_size, void* d_ws, size_t ws_size,
                              hipStream_t stream) {
    const float* x    = (const float*)d_in[0];
    const int*   ei   = (const int*)d_in[1];
    const float* W1l  = (const float*)d_in[2];
    const float* W1r  = (const float*)d_in[3];
    const float* att1 = (const float*)d_in[4];
    const float* b1   = (const float*)d_in[5];
    const float* W2l  = (const float*)d_in[6];
    const float* W2r  = (const float*)d_in[7];
    const float* att2 = (const float*)d_in[8];
    const float* b2   = (const float*)d_in[9];
    float* out = (float*)d_out;

    char* p = (char*)d_ws;
    auto alloc = [&](size_t bytes) {
        char* r = p;
        p += (bytes + 255) & ~(size_t)255;
        return r;
    };
    int* deg      = (int*)alloc((size_t)NN * 4);
    int* rowptr   = (int*)alloc((size_t)(NN + 1) * 4);
    int* bsum     = (int*)alloc((size_t)NB * 4);
    int* cursor   = (int*)alloc((size_t)NN * 4);
    int* col      = (int*)alloc((size_t)NE * 4);
    float* xl1    = (float*)alloc((size_t)NN * 256 * 4);  // reused as xl2
    float* xr1    = (float*)alloc((size_t)NN * 256 * 4);  // reused as xr2
    float* h1     = (float*)alloc((size_t)NN * 256 * 4);

    hipMemsetAsync(deg, 0, (size_t)NN * 4, stream);
    int egrid = (NE + 255) / 256;
    k_hist<<<egrid, 256, 0, stream>>>(ei, deg);
    k_scan_block<<<NB, 256, 0, stream>>>(deg, rowptr, bsum);
    k_scan_top<<<1, 256, 0, stream>>>(bsum);
    k_scan_add<<<NB, 256, 0, stream>>>(rowptr, bsum, cursor);
    k_scatter<<<egrid, 256, 0, stream>>>(ei, cursor, col);

    k_gemm2<128, 256><<<(NN + 15) / 16, 256, 0, stream>>>(x, W1l, W1r, xl1, xr1);
    k_gat1<<<(NN + 3) / 4, 256, 0, stream>>>(xl1, xr1, att1, b1, rowptr, col, h1);
    k_gemm2<256, 128><<<(NN + 31) / 32, 256, 0, stream>>>(h1, W2l, W2r, xl1, xr1);
    k_gat2<<<(NN + 3) / 4, 256, 0, stream>>>(xl1, xr1, att2, b2, rowptr, col, out);
}

// Round 5
// 527.302 us; speedup vs baseline: 1.1196x; 1.1196x over previous
//
#include <hip/hip_runtime.h>
#include <math.h>

// GATv2 2-layer: N=50000 nodes, E=600000 edges, heads=8, C1=32, C2=16.
// CSR build -> MFMA-bf16 GEMM(xl1,xr1) -> GAT1(+ELU, bf16 out) ->
// MFMA-bf16 GEMM(xl2,xr2) -> GAT2(+log_softmax).
constexpr int NN = 50000;
constexpr int NE = 600000;
constexpr int NB = (NN + 255) / 256;

typedef __bf16 bf16x8 __attribute__((ext_vector_type(8)));
typedef float f32x4 __attribute__((ext_vector_type(4)));

__device__ inline unsigned short f2bf(float f) {
    unsigned int u = __float_as_uint(f);
    u += 0x7fffu + ((u >> 16) & 1u);   // RNE
    return (unsigned short)(u >> 16);
}

// ---------------- CSR build ----------------
__global__ __launch_bounds__(256) void k_hist(const int* __restrict__ ei,
                                              int* __restrict__ deg) {
    int e = blockIdx.x * 256 + threadIdx.x;
    if (e < NE) atomicAdd(&deg[ei[NE + e]], 1);
}

__global__ __launch_bounds__(256) void k_scan_block(const int* __restrict__ deg,
                                                    int* __restrict__ rowptr,
                                                    int* __restrict__ bsum) {
    __shared__ int s[256];
    int tid = threadIdx.x;
    int i = blockIdx.x * 256 + tid;
    int v = (i < NN) ? deg[i] : 0;
    s[tid] = v;
    __syncthreads();
    #pragma unroll
    for (int off = 1; off < 256; off <<= 1) {
        int t = (tid >= off) ? s[tid - off] : 0;
        __syncthreads();
        s[tid] += t;
        __syncthreads();
    }
    if (i < NN) rowptr[i] = s[tid] - v;
    if (tid == 255) bsum[blockIdx.x] = s[255];
}

__global__ __launch_bounds__(256) void k_scan_top(int* __restrict__ bsum) {
    __shared__ int s[256];
    int tid = threadIdx.x;
    int v = (tid < NB) ? bsum[tid] : 0;
    s[tid] = v;
    __syncthreads();
    #pragma unroll
    for (int off = 1; off < 256; off <<= 1) {
        int t = (tid >= off) ? s[tid - off] : 0;
        __syncthreads();
        s[tid] += t;
        __syncthreads();
    }
    if (tid < NB) bsum[tid] = s[tid] - v;
}

__global__ __launch_bounds__(256) void k_scan_add(int* __restrict__ rowptr,
                                                  const int* __restrict__ bsum,
                                                  int* __restrict__ cursor) {
    int i = blockIdx.x * 256 + threadIdx.x;
    if (i < NN) {
        int r = rowptr[i] + bsum[blockIdx.x];
        rowptr[i] = r;
        cursor[i] = r;
    }
    if (i == 0) rowptr[NN] = NE;
}

__global__ __launch_bounds__(256) void k_scatter(const int* __restrict__ ei,
                                                 int* __restrict__ cursor,
                                                 int* __restrict__ col) {
    int e = blockIdx.x * 256 + threadIdx.x;
    if (e < NE) {
        int s = ei[e];
        int d = ei[NE + e];
        int p = atomicAdd(&cursor[d], 1);
        col[p] = s;
    }
}

// ---------------- MFMA bf16 dual GEMM ----------------
// Y[:, half] = X @ W{l,r}; X:[NN,K] (f32 or bf16-as-ushort), W:[K,Mw] f32.
// Block: 64 rows x 128 cols; 4 waves, each 16 rows x 128 cols.
// Whole K staged in LDS, +8 bf16 pad per row (2-way-free bank pattern).
// grid.y = 2*nt_half col-tiles; tile t<nt_half -> Wl/Yl else Wr/Yr.
template <int K, typename TIN>
__global__ __launch_bounds__(256) void k_gemm_mfma(const TIN* __restrict__ X,
                                                   const float* __restrict__ Wl,
                                                   const float* __restrict__ Wr,
                                                   float* __restrict__ Yl,
                                                   float* __restrict__ Yr,
                                                   int nt_half, int Mw) {
    constexpr int KP = K + 8;
    __shared__ unsigned short As[64 * KP];
    __shared__ unsigned short Bs[128 * KP];

    int tid = threadIdx.x;
    int row0 = blockIdx.x * 64;
    int t = blockIdx.y;
    const float* W = (t < nt_half) ? Wl : Wr;
    float* Y = (t < nt_half) ? Yl : Yr;
    int cb = ((t < nt_half) ? t : (t - nt_half)) * 128;

    // stage A (64 rows x K), convert to bf16 if f32 input
    for (int i = tid; i < 64 * K / 4; i += 256) {
        int idx = i * 4;
        int r = idx / K, c = idx % K;
        int gr = row0 + r;
        ushort4 v = make_ushort4(0, 0, 0, 0);
        if (gr < NN) {
            if constexpr (sizeof(TIN) == 4) {
                float4 x4 = *(const float4*)((const float*)X + (size_t)gr * K + c);
                v = make_ushort4(f2bf(x4.x), f2bf(x4.y), f2bf(x4.z), f2bf(x4.w));
            } else {
                v = *(const ushort4*)((const unsigned short*)X + (size_t)gr * K + c);
            }
        }
        *(ushort4*)&As[r * KP + c] = v;
    }
    // stage B transposed: Bs[col][k], 2 k per thread-iter (ushort2 writes)
    for (int i = tid; i < 128 * K / 2; i += 256) {
        int c = i & 127;
        int kk = (i >> 7) * 2;
        unsigned short v0 = f2bf(W[(size_t)kk * Mw + cb + c]);
        unsigned short v1 = f2bf(W[(size_t)(kk + 1) * Mw + cb + c]);
        *(ushort2*)&Bs[c * KP + kk] = make_ushort2(v0, v1);
    }
    __syncthreads();

    int wid = tid >> 6, lane = tid & 63;
    int lr = lane & 15, lg = lane >> 4;
    const unsigned short* ap = As + (wid * 16 + lr) * KP + lg * 8;
    const unsigned short* bp = Bs + lr * KP + lg * 8;

    f32x4 acc[8];
    #pragma unroll
    for (int f = 0; f < 8; ++f) acc[f] = (f32x4){0.f, 0.f, 0.f, 0.f};

    #pragma unroll
    for (int ks = 0; ks < K / 32; ++ks) {
        bf16x8 a = *(const bf16x8*)(ap + ks * 32);
        #pragma unroll
        for (int f = 0; f < 8; ++f) {
            bf16x8 b = *(const bf16x8*)(bp + f * 16 * KP + ks * 32);
            acc[f] = __builtin_amdgcn_mfma_f32_16x16x32_bf16(a, b, acc[f], 0, 0, 0);
        }
    }

    #pragma unroll
    for (int f = 0; f < 8; ++f) {
        #pragma unroll
        for (int r = 0; r < 4; ++r) {
            int row = row0 + wid * 16 + lg * 4 + r;
            if (row < NN) Y[(size_t)row * Mw + cb + f * 16 + lr] = acc[f][r];
        }
    }
}

// ---------------- GAT layer 1 (bf16 output for GEMM2) ----------------
__global__ __launch_bounds__(256) void k_gat1(const float* __restrict__ xl,
                                              const float* __restrict__ xr,
                                              const float* __restrict__ att,
                                              const float* __restrict__ bias,
                                              const int* __restrict__ rowptr,
                                              const int* __restrict__ col,
                                              unsigned short* __restrict__ hout) {
    int wv = blockIdx.x * 4 + (threadIdx.x >> 6);
    if (wv >= NN) return;
    int lane = threadIdx.x & 63;
    int c0 = lane * 4;

    float4 xr4 = *(const float4*)(xr + (size_t)wv * 256 + c0);
    float4 a4 = *(const float4*)(att + c0);
    float4 acc = make_float4(0.f, 0.f, 0.f, 0.f);
    float mrun = -1e30f, lrun = 0.f;

    int beg = rowptr[wv], end = rowptr[wv + 1];
    for (int idx = beg; idx <= end; ++idx) {         // <= : implicit self loop
        int src = (idx < end) ? col[idx] : wv;
        float4 m4 = *(const float4*)(xl + (size_t)src * 256 + c0);
        float sx = m4.x + xr4.x; sx = sx > 0.f ? sx : 0.2f * sx;
        float sy = m4.y + xr4.y; sy = sy > 0.f ? sy : 0.2f * sy;
        float sz = m4.z + xr4.z; sz = sz > 0.f ? sz : 0.2f * sz;
        float sw = m4.w + xr4.w; sw = sw > 0.f ? sw : 0.2f * sw;
        float p = sx * a4.x + sy * a4.y + sz * a4.z + sw * a4.w;
        p += __shfl_xor(p, 1);
        p += __shfl_xor(p, 2);
        p += __shfl_xor(p, 4);
        float nm = fmaxf(mrun, p);
        float sc = __expf(mrun - nm);
        float w = __expf(p - nm);
        acc.x = acc.x * sc + m4.x * w;
        acc.y = acc.y * sc + m4.y * w;
        acc.z = acc.z * sc + m4.z * w;
        acc.w = acc.w * sc + m4.w * w;
        lrun = lrun * sc + w;
        mrun = nm;
    }
    float inv = 1.f / lrun;
    float4 b4 = *(const float4*)(bias + c0);
    float ox = acc.x * inv + b4.x; ox = ox > 0.f ? ox : (__expf(ox) - 1.f);  // ELU
    float oy = acc.y * inv + b4.y; oy = oy > 0.f ? oy : (__expf(oy) - 1.f);
    float oz = acc.z * inv + b4.z; oz = oz > 0.f ? oz : (__expf(oz) - 1.f);
    float ow = acc.w * inv + b4.w; ow = ow > 0.f ? ow : (__expf(ow) - 1.f);
    *(ushort4*)(hout + (size_t)wv * 256 + c0) =
        make_ushort4(f2bf(ox), f2bf(oy), f2bf(oz), f2bf(ow));
}

// ---------------- GAT layer 2 + log_softmax ----------------
__global__ __launch_bounds__(256) void k_gat2(const float* __restrict__ xl,
                                              const float* __restrict__ xr,
                                              const float* __restrict__ att,
                                              const float* __restrict__ bias,
                                              const int* __restrict__ rowptr,
                                              const int* __restrict__ col,
                                              float* __restrict__ out) {
    int wv = blockIdx.x * 4 + (threadIdx.x >> 6);
    if (wv >= NN) return;
    int lane = threadIdx.x & 63;
    int c0 = lane * 2;

    float2 xr2 = *(const float2*)(xr + (size_t)wv * 128 + c0);
    float2 a2 = *(const float2*)(att + c0);
    float ax = 0.f, ay = 0.f;
    float mrun = -1e30f, lrun = 0.f;

    int beg = rowptr[wv], end = rowptr[wv + 1];
    for (int idx = beg; idx <= end; ++idx) {
        int src = (idx < end) ? col[idx] : wv;
        float2 m2 = *(const float2*)(xl + (size_t)src * 128 + c0);
        float sx = m2.x + xr2.x; sx = sx > 0.f ? sx : 0.2f * sx;
        float sy = m2.y + xr2.y; sy = sy > 0.f ? sy : 0.2f * sy;
        float p = sx * a2.x + sy * a2.y;
        p += __shfl_xor(p, 1);
        p += __shfl_xor(p, 2);
        p += __shfl_xor(p, 4);
        float nm = fmaxf(mrun, p);
        float sc = __expf(mrun - nm);
        float w = __expf(p - nm);
        ax = ax * sc + m2.x * w;
        ay = ay * sc + m2.y * w;
        lrun = lrun * sc + w;
        mrun = nm;
    }
    float inv = 1.f / lrun;
    float ox = ax * inv + bias[c0];
    float oy = ay * inv + bias[c0 + 1];

    float mx = fmaxf(ox, oy);
    #pragma unroll
    for (int off = 1; off < 64; off <<= 1) mx = fmaxf(mx, __shfl_xor(mx, off));
    float se = __expf(ox - mx) + __expf(oy - mx);
    #pragma unroll
    for (int off = 1; off < 64; off <<= 1) se += __shfl_xor(se, off);
    float lse = mx + logf(se);

    out[(size_t)wv * 128 + c0] = ox - lse;
    out[(size_t)wv * 128 + c0 + 1] = oy - lse;
}

// ---------------- launch ----------------
extern "C" void kernel_launch(void* const* d_in, const int* in_sizes, int n_in,
                              void* d_out, int out_size, void* d_ws, size_t ws_size,
                              hipStream_t stream) {
    const float* x    = (const float*)d_in[0];
    const int*   ei   = (const int*)d_in[1];
    const float* W1l  = (const float*)d_in[2];
    const float* W1r  = (const float*)d_in[3];
    const float* att1 = (const float*)d_in[4];
    const float* b1   = (const float*)d_in[5];
    const float* W2l  = (const float*)d_in[6];
    const float* W2r  = (const float*)d_in[7];
    const float* att2 = (const float*)d_in[8];
    const float* b2   = (const float*)d_in[9];
    float* out = (float*)d_out;

    char* p = (char*)d_ws;
    auto alloc = [&](size_t bytes) {
        char* r = p;
        p += (bytes + 255) & ~(size_t)255;
        return r;
    };
    int* deg      = (int*)alloc((size_t)NN * 4);
    int* rowptr   = (int*)alloc((size_t)(NN + 1) * 4);
    int* bsum     = (int*)alloc((size_t)NB * 4);
    int* cursor   = (int*)alloc((size_t)NN * 4);
    int* col      = (int*)alloc((size_t)NE * 4);
    float* xl1    = (float*)alloc((size_t)NN * 256 * 4);   // reused as xl2
    float* xr1    = (float*)alloc((size_t)NN * 256 * 4);   // reused as xr2
    unsigned short* h1b = (unsigned short*)alloc((size_t)NN * 256 * 2);

    hipMemsetAsync(deg, 0, (size_t)NN * 4, stream);
    int egrid = (NE + 255) / 256;
    k_hist<<<egrid, 256, 0, stream>>>(ei, deg);
    k_scan_block<<<NB, 256, 0, stream>>>(deg, rowptr, bsum);
    k_scan_top<<<1, 256, 0, stream>>>(bsum);
    k_scan_add<<<NB, 256, 0, stream>>>(rowptr, bsum, cursor);
    k_scatter<<<egrid, 256, 0, stream>>>(ei, cursor, col);

    int rblk = (NN + 63) / 64;  // 782
    // layer 1: K=128, per-half width 256 -> 2 col-tiles/half, grid.y=4
    k_gemm_mfma<128, float><<<dim3(rblk, 4), 256, 0, stream>>>(
        x, W1l, W1r, xl1, xr1, 2, 256);
    k_gat1<<<(NN + 3) / 4, 256, 0, stream>>>(xl1, xr1, att1, b1, rowptr, col, h1b);
    // layer 2: K=256, per-half width 128 -> 1 col-tile/half, grid.y=2
    k_gemm_mfma<256, unsigned short><<<dim3(rblk, 2), 256, 0, stream>>>(
        h1b, W2l, W2r, xl1, xr1, 1, 128);
    k_gat2<<<(NN + 3) / 4, 256, 0, stream>>>(xl1, xr1, att2, b2, rowptr, col, out);
}

// Round 6
// 471.463 us; speedup vs baseline: 1.2522x; 1.1184x over previous
//
#include <hip/hip_runtime.h>
#include <math.h>

// GATv2 2-layer: N=50000, E=600000, heads=8, C1=32, C2=16.
// CSR build -> prep (x->bf16, W->bf16 transposed) -> MFMA GEMM1 ->
// GAT1(+ELU, bf16) -> MFMA GEMM2 -> GAT2(+log_softmax).
constexpr int NN = 50000;
constexpr int NE = 600000;
constexpr int NB = (NN + 255) / 256;

typedef __bf16 bf16x8 __attribute__((ext_vector_type(8)));
typedef float f32x4 __attribute__((ext_vector_type(4)));

__device__ inline unsigned short f2bf(float f) {
    unsigned int u = __float_as_uint(f);
    u += 0x7fffu + ((u >> 16) & 1u);   // RNE
    return (unsigned short)(u >> 16);
}
__device__ inline float bf2f(unsigned short s) {
    return __uint_as_float((unsigned int)s << 16);
}

// ---------------- CSR build ----------------
__global__ __launch_bounds__(256) void k_hist(const int* __restrict__ ei,
                                              int* __restrict__ deg) {
    int e = blockIdx.x * 256 + threadIdx.x;
    if (e < NE) atomicAdd(&deg[ei[NE + e]], 1);
}

__global__ __launch_bounds__(256) void k_scan_block(const int* __restrict__ deg,
                                                    int* __restrict__ rowptr,
                                                    int* __restrict__ bsum) {
    __shared__ int s[256];
    int tid = threadIdx.x;
    int i = blockIdx.x * 256 + tid;
    int v = (i < NN) ? deg[i] : 0;
    s[tid] = v;
    __syncthreads();
    #pragma unroll
    for (int off = 1; off < 256; off <<= 1) {
        int t = (tid >= off) ? s[tid - off] : 0;
        __syncthreads();
        s[tid] += t;
        __syncthreads();
    }
    if (i < NN) rowptr[i] = s[tid] - v;
    if (tid == 255) bsum[blockIdx.x] = s[255];
}

__global__ __launch_bounds__(256) void k_scan_top(int* __restrict__ bsum) {
    __shared__ int s[256];
    int tid = threadIdx.x;
    int v = (tid < NB) ? bsum[tid] : 0;
    s[tid] = v;
    __syncthreads();
    #pragma unroll
    for (int off = 1; off < 256; off <<= 1) {
        int t = (tid >= off) ? s[tid - off] : 0;
        __syncthreads();
        s[tid] += t;
        __syncthreads();
    }
    if (tid < NB) bsum[tid] = s[tid] - v;
}

__global__ __launch_bounds__(256) void k_scan_add(int* __restrict__ rowptr,
                                                  const int* __restrict__ bsum,
                                                  int* __restrict__ cursor) {
    int i = blockIdx.x * 256 + threadIdx.x;
    if (i < NN) {
        int r = rowptr[i] + bsum[blockIdx.x];
        rowptr[i] = r;
        cursor[i] = r;
    }
    if (i == 0) rowptr[NN] = NE;
}

__global__ __launch_bounds__(256) void k_scatter(const int* __restrict__ ei,
                                                 int* __restrict__ cursor,
                                                 int* __restrict__ col) {
    int e = blockIdx.x * 256 + threadIdx.x;
    if (e < NE) {
        int s = ei[e];
        int d = ei[NE + e];
        int p = atomicAdd(&cursor[d], 1);
        col[p] = s;
    }
}

// ---------------- prep: f32 -> bf16 convert / W transpose ----------------
__global__ __launch_bounds__(256) void k_cvt_x(const float* __restrict__ x,
                                               unsigned short* __restrict__ xb,
                                               int n4) {
    int i = blockIdx.x * 256 + threadIdx.x;
    if (i < n4) {
        float4 v = *(const float4*)(x + (size_t)i * 4);
        *(ushort4*)(xb + (size_t)i * 4) =
            make_ushort4(f2bf(v.x), f2bf(v.y), f2bf(v.z), f2bf(v.w));
    }
}

// Wt[c*K + k] = bf16( c<M ? Wl[k*M+c] : Wr[k*M+c-M] ), c in [0,2M)
__global__ __launch_bounds__(256) void k_prep_w(const float* __restrict__ Wl,
                                                const float* __restrict__ Wr,
                                                unsigned short* __restrict__ Wt,
                                                int K, int M) {
    int i = blockIdx.x * 256 + threadIdx.x;
    if (i >= 2 * M * K) return;
    int c = i / K, k = i - c * K;
    float v = (c < M) ? Wl[(size_t)k * M + c] : Wr[(size_t)k * M + (c - M)];
    Wt[i] = f2bf(v);
}

// ---------------- MFMA bf16 dual GEMM (A in LDS, B direct from L2) ----------
// Xb:[NN,K] bf16. Wt:[2*Mh,K] bf16 pretransposed (l cols then r cols).
// Yl:[NN,Mh] bf16, Yr:[NN,Mh] f32. Block = 64 rows x 128 combined cols.
// grid.y = 2*Mh/128 col-tiles.
template <int K>
__global__ __launch_bounds__(256) void k_gemm_mfma(
        const unsigned short* __restrict__ Xb,
        const unsigned short* __restrict__ Wt,
        unsigned short* __restrict__ Yl,
        float* __restrict__ Yr,
        int Mh) {
    constexpr int KP = K + 8;                 // pad: 2-way bank alias only (free)
    __shared__ unsigned short As[64 * KP];

    int tid = threadIdx.x;
    int row0 = blockIdx.x * 64;
    int ct0 = blockIdx.y * 128;               // combined col base

    for (int i = tid; i < 64 * K / 4; i += 256) {
        int idx = i * 4;
        int r = idx / K, c = idx - r * K;
        int gr = row0 + r;
        ushort4 v = make_ushort4(0, 0, 0, 0);
        if (gr < NN) v = *(const ushort4*)(Xb + (size_t)gr * K + c);
        *(ushort4*)&As[r * KP + c] = v;
    }
    __syncthreads();

    int wid = tid >> 6, lane = tid & 63;
    int lr = lane & 15, lg = lane >> 4;
    const unsigned short* ap = As + (wid * 16 + lr) * KP + lg * 8;
    const unsigned short* bp = Wt + (size_t)(ct0 + lr) * K + lg * 8;

    f32x4 acc[8];
    #pragma unroll
    for (int f = 0; f < 8; ++f) acc[f] = (f32x4){0.f, 0.f, 0.f, 0.f};

    #pragma unroll
    for (int ks = 0; ks < K / 32; ++ks) {
        bf16x8 a = *(const bf16x8*)(ap + ks * 32);
        #pragma unroll
        for (int f = 0; f < 8; ++f) {
            bf16x8 b = *(const bf16x8*)(bp + (size_t)f * 16 * K + ks * 32);
            acc[f] = __builtin_amdgcn_mfma_f32_16x16x32_bf16(a, b, acc[f], 0, 0, 0);
        }
    }

    bool isL = (ct0 < Mh);
    int cb = isL ? ct0 : (ct0 - Mh);
    #pragma unroll
    for (int f = 0; f < 8; ++f) {
        #pragma unroll
        for (int r = 0; r < 4; ++r) {
            int row = row0 + wid * 16 + lg * 4 + r;
            if (row < NN) {
                int c = cb + f * 16 + lr;
                if (isL) Yl[(size_t)row * Mh + c] = f2bf(acc[f][r]);
                else     Yr[(size_t)row * Mh + c] = acc[f][r];
            }
        }
    }
}

// ---------------- GAT layer 1 (bf16 xl gather, bf16 out) ----------------
__global__ __launch_bounds__(256) void k_gat1(const unsigned short* __restrict__ xl,
                                              const float* __restrict__ xr,
                                              const float* __restrict__ att,
                                              const float* __restrict__ bias,
                                              const int* __restrict__ rowptr,
                                              const int* __restrict__ col,
                                              unsigned short* __restrict__ hout) {
    int wv = blockIdx.x * 4 + (threadIdx.x >> 6);
    if (wv >= NN) return;
    int lane = threadIdx.x & 63;
    int c0 = lane * 4;

    float4 xr4 = *(const float4*)(xr + (size_t)wv * 256 + c0);
    float4 a4 = *(const float4*)(att + c0);
    float4 acc = make_float4(0.f, 0.f, 0.f, 0.f);
    float mrun = -1e30f, lrun = 0.f;

    int beg = rowptr[wv], end = rowptr[wv + 1];
    for (int idx = beg; idx <= end; ++idx) {         // <= : implicit self loop
        int src = (idx < end) ? col[idx] : wv;
        ushort4 mv = *(const ushort4*)(xl + (size_t)src * 256 + c0);
        float m0 = bf2f(mv.x), m1 = bf2f(mv.y), m2 = bf2f(mv.z), m3 = bf2f(mv.w);
        float sx = m0 + xr4.x; sx = sx > 0.f ? sx : 0.2f * sx;
        float sy = m1 + xr4.y; sy = sy > 0.f ? sy : 0.2f * sy;
        float sz = m2 + xr4.z; sz = sz > 0.f ? sz : 0.2f * sz;
        float sw = m3 + xr4.w; sw = sw > 0.f ? sw : 0.2f * sw;
        float p = sx * a4.x + sy * a4.y + sz * a4.z + sw * a4.w;
        p += __shfl_xor(p, 1);
        p += __shfl_xor(p, 2);
        p += __shfl_xor(p, 4);
        float nm = fmaxf(mrun, p);
        float sc = __expf(mrun - nm);
        float w = __expf(p - nm);
        acc.x = acc.x * sc + m0 * w;
        acc.y = acc.y * sc + m1 * w;
        acc.z = acc.z * sc + m2 * w;
        acc.w = acc.w * sc + m3 * w;
        lrun = lrun * sc + w;
        mrun = nm;
    }
    float inv = 1.f / lrun;
    float4 b4 = *(const float4*)(bias + c0);
    float ox = acc.x * inv + b4.x; ox = ox > 0.f ? ox : (__expf(ox) - 1.f);  // ELU
    float oy = acc.y * inv + b4.y; oy = oy > 0.f ? oy : (__expf(oy) - 1.f);
    float oz = acc.z * inv + b4.z; oz = oz > 0.f ? oz : (__expf(oz) - 1.f);
    float ow = acc.w * inv + b4.w; ow = ow > 0.f ? ow : (__expf(ow) - 1.f);
    *(ushort4*)(hout + (size_t)wv * 256 + c0) =
        make_ushort4(f2bf(ox), f2bf(oy), f2bf(oz), f2bf(ow));
}

// ---------------- GAT layer 2 + log_softmax (bf16 xl gather) ----------------
__global__ __launch_bounds__(256) void k_gat2(const unsigned short* __restrict__ xl,
                                              const float* __restrict__ xr,
                                              const float* __restrict__ att,
                                              const float* __restrict__ bias,
                                              const int* __restrict__ rowptr,
                                              const int* __restrict__ col,
                                              float* __restrict__ out) {
    int wv = blockIdx.x * 4 + (threadIdx.x >> 6);
    if (wv >= NN) return;
    int lane = threadIdx.x & 63;
    int c0 = lane * 2;

    float2 xr2 = *(const float2*)(xr + (size_t)wv * 128 + c0);
    float2 a2 = *(const float2*)(att + c0);
    float ax = 0.f, ay = 0.f;
    float mrun = -1e30f, lrun = 0.f;

    int beg = rowptr[wv], end = rowptr[wv + 1];
    for (int idx = beg; idx <= end; ++idx) {
        int src = (idx < end) ? col[idx] : wv;
        ushort2 mv = *(const ushort2*)(xl + (size_t)src * 128 + c0);
        float m0 = bf2f(mv.x), m1 = bf2f(mv.y);
        float sx = m0 + xr2.x; sx = sx > 0.f ? sx : 0.2f * sx;
        float sy = m1 + xr2.y; sy = sy > 0.f ? sy : 0.2f * sy;
        float p = sx * a2.x + sy * a2.y;
        p += __shfl_xor(p, 1);
        p += __shfl_xor(p, 2);
        p += __shfl_xor(p, 4);
        float nm = fmaxf(mrun, p);
        float sc = __expf(mrun - nm);
        float w = __expf(p - nm);
        ax = ax * sc + m0 * w;
        ay = ay * sc + m1 * w;
        lrun = lrun * sc + w;
        mrun = nm;
    }
    float inv = 1.f / lrun;
    float ox = ax * inv + bias[c0];
    float oy = ay * inv + bias[c0 + 1];

    float mx = fmaxf(ox, oy);
    #pragma unroll
    for (int off = 1; off < 64; off <<= 1) mx = fmaxf(mx, __shfl_xor(mx, off));
    float se = __expf(ox - mx) + __expf(oy - mx);
    #pragma unroll
    for (int off = 1; off < 64; off <<= 1) se += __shfl_xor(se, off);
    float lse = mx + logf(se);

    out[(size_t)wv * 128 + c0] = ox - lse;
    out[(size_t)wv * 128 + c0 + 1] = oy - lse;
}

// ---------------- launch ----------------
extern "C" void kernel_launch(void* const* d_in, const int* in_sizes, int n_in,
                              void* d_out, int out_size, void* d_ws, size_t ws_size,
                              hipStream_t stream) {
    const float* x    = (const float*)d_in[0];
    const int*   ei   = (const int*)d_in[1];
    const float* W1l  = (const float*)d_in[2];
    const float* W1r  = (const float*)d_in[3];
    const float* att1 = (const float*)d_in[4];
    const float* b1   = (const float*)d_in[5];
    const float* W2l  = (const float*)d_in[6];
    const float* W2r  = (const float*)d_in[7];
    const float* att2 = (const float*)d_in[8];
    const float* b2   = (const float*)d_in[9];
    float* out = (float*)d_out;

    char* p = (char*)d_ws;
    auto alloc = [&](size_t bytes) {
        char* r = p;
        p += (bytes + 255) & ~(size_t)255;
        return r;
    };
    int* deg      = (int*)alloc((size_t)NN * 4);
    int* rowptr   = (int*)alloc((size_t)(NN + 1) * 4);
    int* bsum     = (int*)alloc((size_t)NB * 4);
    int* cursor   = (int*)alloc((size_t)NN * 4);
    int* col      = (int*)alloc((size_t)NE * 4);
    unsigned short* xb   = (unsigned short*)alloc((size_t)NN * 128 * 2);
    unsigned short* Wt1  = (unsigned short*)alloc((size_t)512 * 128 * 2);
    unsigned short* Wt2  = (unsigned short*)alloc((size_t)256 * 256 * 2);
    unsigned short* xl1b = (unsigned short*)alloc((size_t)NN * 256 * 2);
    float*          xr1  = (float*)alloc((size_t)NN * 256 * 4);
    unsigned short* h1b  = (unsigned short*)alloc((size_t)NN * 256 * 2);
    unsigned short* xl2b = (unsigned short*)alloc((size_t)NN * 128 * 2);
    float*          xr2  = (float*)alloc((size_t)NN * 128 * 4);

    hipMemsetAsync(deg, 0, (size_t)NN * 4, stream);
    int egrid = (NE + 255) / 256;
    k_hist<<<egrid, 256, 0, stream>>>(ei, deg);
    k_scan_block<<<NB, 256, 0, stream>>>(deg, rowptr, bsum);
    k_scan_top<<<1, 256, 0, stream>>>(bsum);
    k_scan_add<<<NB, 256, 0, stream>>>(rowptr, bsum, cursor);
    k_scatter<<<egrid, 256, 0, stream>>>(ei, cursor, col);

    // prep
    int n4 = NN * 128 / 4;
    k_cvt_x<<<(n4 + 255) / 256, 256, 0, stream>>>(x, xb, n4);
    k_prep_w<<<(2 * 256 * 128 + 255) / 256, 256, 0, stream>>>(W1l, W1r, Wt1, 128, 256);
    k_prep_w<<<(2 * 128 * 256 + 255) / 256, 256, 0, stream>>>(W2l, W2r, Wt2, 256, 128);

    int rblk = (NN + 63) / 64;  // 782
    k_gemm_mfma<128><<<dim3(rblk, 4), 256, 0, stream>>>(xb, Wt1, xl1b, xr1, 256);
    k_gat1<<<(NN + 3) / 4, 256, 0, stream>>>(xl1b, xr1, att1, b1, rowptr, col, h1b);
    k_gemm_mfma<256><<<dim3(rblk, 2), 256, 0, stream>>>(h1b, Wt2, xl2b, xr2, 128);
    k_gat2<<<(NN + 3) / 4, 256, 0, stream>>>(xl2b, xr2, att2, b2, rowptr, col, out);
}

// Round 9
// 397.750 us; speedup vs baseline: 1.4842x; 1.1853x over previous
//
#include <hip/hip_runtime.h>
#include <math.h>

// GATv2 2-layer: N=50000, E=600000, heads=8, C1=32, C2=16.
// CSR build -> prep (x->bf16, W->bf16 transposed) -> MFMA GEMM1 ->
// GAT1(+ELU, bf16, 4-edge unroll) -> MFMA GEMM2 -> GAT2(+log_softmax, 4-edge unroll).
constexpr int NN = 50000;
constexpr int NE = 600000;
constexpr int NB = (NN + 255) / 256;

typedef __bf16 bf16x8 __attribute__((ext_vector_type(8)));
typedef float f32x4 __attribute__((ext_vector_type(4)));

__device__ inline unsigned short f2bf(float f) {
    unsigned int u = __float_as_uint(f);
    u += 0x7fffu + ((u >> 16) & 1u);   // RNE
    return (unsigned short)(u >> 16);
}
__device__ inline float bf2f(unsigned short s) {
    return __uint_as_float((unsigned int)s << 16);
}

// ---------------- CSR build ----------------
__global__ __launch_bounds__(256) void k_hist(const int* __restrict__ ei,
                                              int* __restrict__ deg) {
    int e = blockIdx.x * 256 + threadIdx.x;
    if (e < NE) atomicAdd(&deg[ei[NE + e]], 1);
}

__global__ __launch_bounds__(256) void k_scan_block(const int* __restrict__ deg,
                                                    int* __restrict__ rowptr,
                                                    int* __restrict__ bsum) {
    __shared__ int s[256];
    int tid = threadIdx.x;
    int i = blockIdx.x * 256 + tid;
    int v = (i < NN) ? deg[i] : 0;
    s[tid] = v;
    __syncthreads();
    #pragma unroll
    for (int off = 1; off < 256; off <<= 1) {
        int t = (tid >= off) ? s[tid - off] : 0;
        __syncthreads();
        s[tid] += t;
        __syncthreads();
    }
    if (i < NN) rowptr[i] = s[tid] - v;
    if (tid == 255) bsum[blockIdx.x] = s[255];
}

__global__ __launch_bounds__(256) void k_scan_top(int* __restrict__ bsum) {
    __shared__ int s[256];
    int tid = threadIdx.x;
    int v = (tid < NB) ? bsum[tid] : 0;
    s[tid] = v;
    __syncthreads();
    #pragma unroll
    for (int off = 1; off < 256; off <<= 1) {
        int t = (tid >= off) ? s[tid - off] : 0;
        __syncthreads();
        s[tid] += t;
        __syncthreads();
    }
    if (tid < NB) bsum[tid] = s[tid] - v;
}

__global__ __launch_bounds__(256) void k_scan_add(int* __restrict__ rowptr,
                                                  const int* __restrict__ bsum,
                                                  int* __restrict__ cursor) {
    int i = blockIdx.x * 256 + threadIdx.x;
    if (i < NN) {
        int r = rowptr[i] + bsum[blockIdx.x];
        rowptr[i] = r;
        cursor[i] = r;
    }
    if (i == 0) rowptr[NN] = NE;
}

__global__ __launch_bounds__(256) void k_scatter(const int* __restrict__ ei,
                                                 int* __restrict__ cursor,
                                                 int* __restrict__ col) {
    int e = blockIdx.x * 256 + threadIdx.x;
    if (e < NE) {
        int s = ei[e];
        int d = ei[NE + e];
        int p = atomicAdd(&cursor[d], 1);
        col[p] = s;
    }
}

// ---------------- prep: f32 -> bf16 convert / W transpose ----------------
__global__ __launch_bounds__(256) void k_cvt_x(const float* __restrict__ x,
                                               unsigned short* __restrict__ xb,
                                               int n4) {
    int i = blockIdx.x * 256 + threadIdx.x;
    if (i < n4) {
        float4 v = *(const float4*)(x + (size_t)i * 4);
        *(ushort4*)(xb + (size_t)i * 4) =
            make_ushort4(f2bf(v.x), f2bf(v.y), f2bf(v.z), f2bf(v.w));
    }
}

// Wt[c*K + k] = bf16( c<M ? Wl[k*M+c] : Wr[k*M+c-M] ), c in [0,2M)
__global__ __launch_bounds__(256) void k_prep_w(const float* __restrict__ Wl,
                                                const float* __restrict__ Wr,
                                                unsigned short* __restrict__ Wt,
                                                int K, int M) {
    int i = blockIdx.x * 256 + threadIdx.x;
    if (i >= 2 * M * K) return;
    int c = i / K, k = i - c * K;
    float v = (c < M) ? Wl[(size_t)k * M + c] : Wr[(size_t)k * M + (c - M)];
    Wt[i] = f2bf(v);
}

// ---------------- MFMA bf16 dual GEMM (A in LDS, B direct from L2) ----------
template <int K>
__global__ __launch_bounds__(256) void k_gemm_mfma(
        const unsigned short* __restrict__ Xb,
        const unsigned short* __restrict__ Wt,
        unsigned short* __restrict__ Yl,
        float* __restrict__ Yr,
        int Mh) {
    constexpr int KP = K + 8;                 // 2-way bank alias only (free)
    __shared__ unsigned short As[64 * KP];

    int tid = threadIdx.x;
    int row0 = blockIdx.x * 64;
    int ct0 = blockIdx.y * 128;               // combined col base

    for (int i = tid; i < 64 * K / 4; i += 256) {
        int idx = i * 4;
        int r = idx / K, c = idx - r * K;
        int gr = row0 + r;
        ushort4 v = make_ushort4(0, 0, 0, 0);
        if (gr < NN) v = *(const ushort4*)(Xb + (size_t)gr * K + c);
        *(ushort4*)&As[r * KP + c] = v;
    }
    __syncthreads();

    int wid = tid >> 6, lane = tid & 63;
    int lr = lane & 15, lg = lane >> 4;
    const unsigned short* ap = As + (wid * 16 + lr) * KP + lg * 8;
    const unsigned short* bp = Wt + (size_t)(ct0 + lr) * K + lg * 8;

    f32x4 acc[8];
    #pragma unroll
    for (int f = 0; f < 8; ++f) acc[f] = (f32x4){0.f, 0.f, 0.f, 0.f};

    #pragma unroll
    for (int ks = 0; ks < K / 32; ++ks) {
        bf16x8 a = *(const bf16x8*)(ap + ks * 32);
        #pragma unroll
        for (int f = 0; f < 8; ++f) {
            bf16x8 b = *(const bf16x8*)(bp + (size_t)f * 16 * K + ks * 32);
            acc[f] = __builtin_amdgcn_mfma_f32_16x16x32_bf16(a, b, acc[f], 0, 0, 0);
        }
    }

    bool isL = (ct0 < Mh);
    int cb = isL ? ct0 : (ct0 - Mh);
    #pragma unroll
    for (int f = 0; f < 8; ++f) {
        #pragma unroll
        for (int r = 0; r < 4; ++r) {
            int row = row0 + wid * 16 + lg * 4 + r;
            if (row < NN) {
                int c = cb + f * 16 + lr;
                if (isL) Yl[(size_t)row * Mh + c] = f2bf(acc[f][r]);
                else     Yr[(size_t)row * Mh + c] = acc[f][r];
            }
        }
    }
}

// ---------------- GAT layer 1: 4-edge unrolled online softmax ----------------
// Per edge: s = leaky(m + xr); p = head-dot(att, s) via 3 shfl_xor.
#define GAT1_EDGE(SRC, MV, P)                                               \
    {                                                                       \
        MV = *(const ushort4*)(xl + (size_t)(SRC) * 256 + c0);              \
        float e0 = bf2f(MV.x) + xr4.x; e0 = e0 > 0.f ? e0 : 0.2f * e0;      \
        float e1 = bf2f(MV.y) + xr4.y; e1 = e1 > 0.f ? e1 : 0.2f * e1;      \
        float e2 = bf2f(MV.z) + xr4.z; e2 = e2 > 0.f ? e2 : 0.2f * e2;      \
        float e3 = bf2f(MV.w) + xr4.w; e3 = e3 > 0.f ? e3 : 0.2f * e3;      \
        P = e0 * a4.x + e1 * a4.y + e2 * a4.z + e3 * a4.w;                  \
        P += __shfl_xor(P, 1);                                              \
        P += __shfl_xor(P, 2);                                              \
        P += __shfl_xor(P, 4);                                              \
    }

__global__ __launch_bounds__(256) void k_gat1(const unsigned short* __restrict__ xl,
                                              const float* __restrict__ xr,
                                              const float* __restrict__ att,
                                              const float* __restrict__ bias,
                                              const int* __restrict__ rowptr,
                                              const int* __restrict__ col,
                                              unsigned short* __restrict__ hout) {
    int wv = blockIdx.x * 4 + (threadIdx.x >> 6);
    if (wv >= NN) return;
    int lane = threadIdx.x & 63;
    int c0 = lane * 4;

    float4 xr4 = *(const float4*)(xr + (size_t)wv * 256 + c0);
    float4 a4 = *(const float4*)(att + c0);

    // self loop initializes running state (weight 1 at its own max)
    ushort4 mvS; float pS;
    GAT1_EDGE(wv, mvS, pS);
    float mrun = pS, lrun = 1.f;
    float4 acc = make_float4(bf2f(mvS.x), bf2f(mvS.y), bf2f(mvS.z), bf2f(mvS.w));

    int beg = rowptr[wv], end = rowptr[wv + 1];
    int idx = beg;
    for (; idx + 4 <= end; idx += 4) {
        int s0 = col[idx], s1 = col[idx + 1], s2 = col[idx + 2], s3 = col[idx + 3];
        ushort4 mv0, mv1, mv2, mv3;
        float p0, p1, p2, p3;
        GAT1_EDGE(s0, mv0, p0);
        GAT1_EDGE(s1, mv1, p1);
        GAT1_EDGE(s2, mv2, p2);
        GAT1_EDGE(s3, mv3, p3);
        float nm = fmaxf(fmaxf(fmaxf(p0, p1), fmaxf(p2, p3)), mrun);
        float sc = __expf(mrun - nm);
        float w0 = __expf(p0 - nm), w1 = __expf(p1 - nm);
        float w2 = __expf(p2 - nm), w3 = __expf(p3 - nm);
        acc.x = acc.x * sc + bf2f(mv0.x) * w0 + bf2f(mv1.x) * w1 + bf2f(mv2.x) * w2 + bf2f(mv3.x) * w3;
        acc.y = acc.y * sc + bf2f(mv0.y) * w0 + bf2f(mv1.y) * w1 + bf2f(mv2.y) * w2 + bf2f(mv3.y) * w3;
        acc.z = acc.z * sc + bf2f(mv0.z) * w0 + bf2f(mv1.z) * w1 + bf2f(mv2.z) * w2 + bf2f(mv3.z) * w3;
        acc.w = acc.w * sc + bf2f(mv0.w) * w0 + bf2f(mv1.w) * w1 + bf2f(mv2.w) * w2 + bf2f(mv3.w) * w3;
        lrun = lrun * sc + w0 + w1 + w2 + w3;
        mrun = nm;
    }
    for (; idx < end; ++idx) {
        int src = col[idx];
        ushort4 mv; float p;
        GAT1_EDGE(src, mv, p);
        float nm = fmaxf(mrun, p);
        float sc = __expf(mrun - nm);
        float w = __expf(p - nm);
        acc.x = acc.x * sc + bf2f(mv.x) * w;
        acc.y = acc.y * sc + bf2f(mv.y) * w;
        acc.z = acc.z * sc + bf2f(mv.z) * w;
        acc.w = acc.w * sc + bf2f(mv.w) * w;
        lrun = lrun * sc + w;
        mrun = nm;
    }

    float inv = 1.f / lrun;
    float4 b4 = *(const float4*)(bias + c0);
    float ox = acc.x * inv + b4.x; ox = ox > 0.f ? ox : (__expf(ox) - 1.f);  // ELU
    float oy = acc.y * inv + b4.y; oy = oy > 0.f ? oy : (__expf(oy) - 1.f);
    float oz = acc.z * inv + b4.z; oz = oz > 0.f ? oz : (__expf(oz) - 1.f);
    float ow = acc.w * inv + b4.w; ow = ow > 0.f ? ow : (__expf(ow) - 1.f);
    *(ushort4*)(hout + (size_t)wv * 256 + c0) =
        make_ushort4(f2bf(ox), f2bf(oy), f2bf(oz), f2bf(ow));
}

// ---------------- GAT layer 2 + log_softmax: 4-edge unrolled ----------------
#define GAT2_EDGE(SRC, MV, P)                                               \
    {                                                                       \
        MV = *(const ushort2*)(xl + (size_t)(SRC) * 128 + c0);              \
        float e0 = bf2f(MV.x) + xr2.x; e0 = e0 > 0.f ? e0 : 0.2f * e0;      \
        float e1 = bf2f(MV.y) + xr2.y; e1 = e1 > 0.f ? e1 : 0.2f * e1;      \
        P = e0 * a2.x + e1 * a2.y;                                          \
        P += __shfl_xor(P, 1);                                              \
        P += __shfl_xor(P, 2);                                              \
        P += __shfl_xor(P, 4);                                              \
    }

__global__ __launch_bounds__(256) void k_gat2(const unsigned short* __restrict__ xl,
                                              const float* __restrict__ xr,
                                              const float* __restrict__ att,
                                              const float* __restrict__ bias,
                                              const int* __restrict__ rowptr,
                                              const int* __restrict__ col,
                                              float* __restrict__ out) {
    int wv = blockIdx.x * 4 + (threadIdx.x >> 6);
    if (wv >= NN) return;
    int lane = threadIdx.x & 63;
    int c0 = lane * 2;

    float2 xr2 = *(const float2*)(xr + (size_t)wv * 128 + c0);
    float2 a2 = *(const float2*)(att + c0);

    ushort2 mvS; float pS;
    GAT2_EDGE(wv, mvS, pS);
    float mrun = pS, lrun = 1.f;
    float ax = bf2f(mvS.x), ay = bf2f(mvS.y);

    int beg = rowptr[wv], end = rowptr[wv + 1];
    int idx = beg;
    for (; idx + 4 <= end; idx += 4) {
        int s0 = col[idx], s1 = col[idx + 1], s2 = col[idx + 2], s3 = col[idx + 3];
        ushort2 mv0, mv1, mv2, mv3;
        float p0, p1, p2, p3;
        GAT2_EDGE(s0, mv0, p0);
        GAT2_EDGE(s1, mv1, p1);
        GAT2_EDGE(s2, mv2, p2);
        GAT2_EDGE(s3, mv3, p3);
        float nm = fmaxf(fmaxf(fmaxf(p0, p1), fmaxf(p2, p3)), mrun);
        float sc = __expf(mrun - nm);
        float w0 = __expf(p0 - nm), w1 = __expf(p1 - nm);
        float w2 = __expf(p2 - nm), w3 = __expf(p3 - nm);
        ax = ax * sc + bf2f(mv0.x) * w0 + bf2f(mv1.x) * w1 + bf2f(mv2.x) * w2 + bf2f(mv3.x) * w3;
        ay = ay * sc + bf2f(mv0.y) * w0 + bf2f(mv1.y) * w1 + bf2f(mv2.y) * w2 + bf2f(mv3.y) * w3;
        lrun = lrun * sc + w0 + w1 + w2 + w3;
        mrun = nm;
    }
    for (; idx < end; ++idx) {
        int src = col[idx];
        ushort2 mv; float p;
        GAT2_EDGE(src, mv, p);
        float nm = fmaxf(mrun, p);
        float sc = __expf(mrun - nm);
        float w = __expf(p - nm);
        ax = ax * sc + bf2f(mv.x) * w;
        ay = ay * sc + bf2f(mv.y) * w;
        lrun = lrun * sc + w;
        mrun = nm;
    }

    float inv = 1.f / lrun;
    float ox = ax * inv + bias[c0];
    float oy = ay * inv + bias[c0 + 1];

    float mx = fmaxf(ox, oy);
    #pragma unroll
    for (int off = 1; off < 64; off <<= 1) mx = fmaxf(mx, __shfl_xor(mx, off));
    float se = __expf(ox - mx) + __expf(oy - mx);
    #pragma unroll
    for (int off = 1; off < 64; off <<= 1) se += __shfl_xor(se, off);
    float lse = mx + logf(se);

    out[(size_t)wv * 128 + c0] = ox - lse;
    out[(size_t)wv * 128 + c0 + 1] = oy - lse;
}

// ---------------- launch ----------------
extern "C" void kernel_launch(void* const* d_in, const int* in_sizes, int n_in,
                              void* d_out, int out_size, void* d_ws, size_t ws_size,
                              hipStream_t stream) {
    const float* x    = (const float*)d_in[0];
    const int*   ei   = (const int*)d_in[1];
    const float* W1l  = (const float*)d_in[2];
    const float* W1r  = (const float*)d_in[3];
    const float* att1 = (const float*)d_in[4];
    const float* b1   = (const float*)d_in[5];
    const float* W2l  = (const float*)d_in[6];
    const float* W2r  = (const float*)d_in[7];
    const float* att2 = (const float*)d_in[8];
    const float* b2   = (const float*)d_in[9];
    float* out = (float*)d_out;

    char* p = (char*)d_ws;
    auto alloc = [&](size_t bytes) {
        char* r = p;
        p += (bytes + 255) & ~(size_t)255;
        return r;
    };
    int* deg      = (int*)alloc((size_t)NN * 4);
    int* rowptr   = (int*)alloc((size_t)(NN + 1) * 4);
    int* bsum     = (int*)alloc((size_t)NB * 4);
    int* cursor   = (int*)alloc((size_t)NN * 4);
    int* col      = (int*)alloc((size_t)NE * 4);
    unsigned short* xb   = (unsigned short*)alloc((size_t)NN * 128 * 2);
    unsigned short* Wt1  = (unsigned short*)alloc((size_t)512 * 128 * 2);
    unsigned short* Wt2  = (unsigned short*)alloc((size_t)256 * 256 * 2);
    unsigned short* xl1b = (unsigned short*)alloc((size_t)NN * 256 * 2);
    float*          xr1  = (float*)alloc((size_t)NN * 256 * 4);
    unsigned short* h1b  = (unsigned short*)alloc((size_t)NN * 256 * 2);
    unsigned short* xl2b = (unsigned short*)alloc((size_t)NN * 128 * 2);
    float*          xr2  = (float*)alloc((size_t)NN * 128 * 4);

    hipMemsetAsync(deg, 0, (size_t)NN * 4, stream);
    int egrid = (NE + 255) / 256;
    k_hist<<<egrid, 256, 0, stream>>>(ei, deg);
    k_scan_block<<<NB, 256, 0, stream>>>(deg, rowptr, bsum);
    k_scan_top<<<1, 256, 0, stream>>>(bsum);
    k_scan_add<<<NB, 256, 0, stream>>>(rowptr, bsum, cursor);
    k_scatter<<<egrid, 256, 0, stream>>>(ei, cursor, col);

    // prep
    int n4 = NN * 128 / 4;
    k_cvt_x<<<(n4 + 255) / 256, 256, 0, stream>>>(x, xb, n4);
    k_prep_w<<<(2 * 256 * 128 + 255) / 256, 256, 0, stream>>>(W1l, W1r, Wt1, 128, 256);
    k_prep_w<<<(2 * 128 * 256 + 255) / 256, 256, 0, stream>>>(W2l, W2r, Wt2, 256, 128);

    int rblk = (NN + 63) / 64;  // 782
    k_gemm_mfma<128><<<dim3(rblk, 4), 256, 0, stream>>>(xb, Wt1, xl1b, xr1, 256);
    k_gat1<<<(NN + 3) / 4, 256, 0, stream>>>(xl1b, xr1, att1, b1, rowptr, col, h1b);
    k_gemm_mfma<256><<<dim3(rblk, 2), 256, 0, stream>>>(h1b, Wt2, xl2b, xr2, 128);
    k_gat2<<<(NN + 3) / 4, 256, 0, stream>>>(xl2b, xr2, att2, b2, rowptr, col, out);
}

// Round 11
// 319.960 us; speedup vs baseline: 1.8451x; 1.2431x over previous
//
#include <hip/hip_runtime.h>
#include <math.h>

// GATv2 2-layer: N=50000, E=600000, heads=8, C1=32, C2=16.
// CSR build -> prep (x->bf16, W->MFMA-fragment-packed bf16) -> MFMA GEMM1 ->
// GAT1(+ELU) -> MFMA GEMM2 -> GAT2(+log_softmax).
// GEMM B-operand is read directly from L2 in fragment-packed order
// (64 lanes x contiguous 16B = coalesced), A staged once per block.
constexpr int NN = 50000;
constexpr int NE = 600000;
constexpr int NB = (NN + 255) / 256;

typedef __bf16 bf16x8 __attribute__((ext_vector_type(8)));
typedef float f32x4 __attribute__((ext_vector_type(4)));

__device__ inline unsigned short f2bf(float f) {
    unsigned int u = __float_as_uint(f);
    u += 0x7fffu + ((u >> 16) & 1u);   // RNE
    return (unsigned short)(u >> 16);
}
__device__ inline float bf2f(unsigned short s) {
    return __uint_as_float((unsigned int)s << 16);
}

// ---------------- CSR build ----------------
__global__ __launch_bounds__(256) void k_hist(const int* __restrict__ ei,
                                              int* __restrict__ deg) {
    int e = blockIdx.x * 256 + threadIdx.x;
    if (e < NE) atomicAdd(&deg[ei[NE + e]], 1);
}

__global__ __launch_bounds__(256) void k_scan_block(const int* __restrict__ deg,
                                                    int* __restrict__ rowptr,
                                                    int* __restrict__ bsum) {
    __shared__ int s[256];
    int tid = threadIdx.x;
    int i = blockIdx.x * 256 + tid;
    int v = (i < NN) ? deg[i] : 0;
    s[tid] = v;
    __syncthreads();
    #pragma unroll
    for (int off = 1; off < 256; off <<= 1) {
        int t = (tid >= off) ? s[tid - off] : 0;
        __syncthreads();
        s[tid] += t;
        __syncthreads();
    }
    if (i < NN) rowptr[i] = s[tid] - v;
    if (tid == 255) bsum[blockIdx.x] = s[255];
}

__global__ __launch_bounds__(256) void k_scan_top(int* __restrict__ bsum) {
    __shared__ int s[256];
    int tid = threadIdx.x;
    int v = (tid < NB) ? bsum[tid] : 0;
    s[tid] = v;
    __syncthreads();
    #pragma unroll
    for (int off = 1; off < 256; off <<= 1) {
        int t = (tid >= off) ? s[tid - off] : 0;
        __syncthreads();
        s[tid] += t;
        __syncthreads();
    }
    if (tid < NB) bsum[tid] = s[tid] - v;
}

__global__ __launch_bounds__(256) void k_scan_add(int* __restrict__ rowptr,
                                                  const int* __restrict__ bsum,
                                                  int* __restrict__ cursor) {
    int i = blockIdx.x * 256 + threadIdx.x;
    if (i < NN) {
        int r = rowptr[i] + bsum[blockIdx.x];
        rowptr[i] = r;
        cursor[i] = r;
    }
    if (i == 0) rowptr[NN] = NE;
}

__global__ __launch_bounds__(256) void k_scatter(const int* __restrict__ ei,
                                                 int* __restrict__ cursor,
                                                 int* __restrict__ col) {
    int e = blockIdx.x * 256 + threadIdx.x;
    if (e < NE) {
        int s = ei[e];
        int d = ei[NE + e];
        int p = atomicAdd(&cursor[d], 1);
        col[p] = s;
    }
}

// ---------------- prep ----------------
__global__ __launch_bounds__(256) void k_cvt_x(const float* __restrict__ x,
                                               unsigned short* __restrict__ xb,
                                               int n4) {
    int i = blockIdx.x * 256 + threadIdx.x;
    if (i < n4) {
        float4 v = *(const float4*)(x + (size_t)i * 4);
        *(ushort4*)(xb + (size_t)i * 4) =
            make_ushort4(f2bf(v.x), f2bf(v.y), f2bf(v.z), f2bf(v.w));
    }
}

// Pack W into MFMA-fragment order:
// Wp[ (((t*8+f)*KS+ks)*64 + l)*8 + j ] = B[k=ks*32+(l>>4)*8+j][c=t*128+f*16+(l&15)]
// where B combined-col c<M -> Wl[k*M+c], else Wr[k*M+c-M].
template <int K, int M, int NT>
__global__ __launch_bounds__(256) void k_prep_w(const float* __restrict__ Wl,
                                                const float* __restrict__ Wr,
                                                unsigned short* __restrict__ Wp) {
    constexpr int KS = K / 32;
    int i = blockIdx.x * 256 + threadIdx.x;
    if (i >= NT * 8 * KS * 512) return;
    int idx = i;
    int j = idx & 7; idx >>= 3;
    int l = idx & 63; idx >>= 6;
    int ks = idx % KS; idx /= KS;
    int f = idx & 7; idx >>= 3;
    int t = idx;
    int k = ks * 32 + (l >> 4) * 8 + j;
    int c = t * 128 + f * 16 + (l & 15);
    float v = (c < M) ? Wl[(size_t)k * M + c] : Wr[(size_t)k * M + (c - M)];
    Wp[i] = f2bf(v);
}

// ---------------- MFMA bf16 dual GEMM ----------------
// Xb:[NN,K] bf16; Wp fragment-packed; Yl,Yr:[NN,Mh] bf16.
// Block = 64 rows; loops over all NT col-tiles (A staged once).
template <int K, int NT>
__global__ __launch_bounds__(256) void k_gemm_mfma(
        const unsigned short* __restrict__ Xb,
        const unsigned short* __restrict__ Wp,
        unsigned short* __restrict__ Yl,
        unsigned short* __restrict__ Yr,
        int Mh) {
    constexpr int KS = K / 32;
    constexpr int KP = K + 8;
    __shared__ unsigned short As[64 * KP];

    int tid = threadIdx.x;
    int row0 = blockIdx.x * 64;

    for (int i = tid; i < 64 * K / 4; i += 256) {
        int idx = i * 4;
        int r = idx / K, c = idx - r * K;
        int gr = row0 + r;
        ushort4 v = make_ushort4(0, 0, 0, 0);
        if (gr < NN) v = *(const ushort4*)(Xb + (size_t)gr * K + c);
        *(ushort4*)&As[r * KP + c] = v;
    }
    __syncthreads();

    int wid = tid >> 6, lane = tid & 63;
    int lr = lane & 15, lg = lane >> 4;
    const unsigned short* ap = As + (wid * 16 + lr) * KP + lg * 8;

    bf16x8 a[KS];
    #pragma unroll
    for (int ks = 0; ks < KS; ++ks) a[ks] = *(const bf16x8*)(ap + ks * 32);

    const unsigned short* bbase = Wp + (size_t)lane * 8;

    for (int t = 0; t < NT; ++t) {
        f32x4 acc[8];
        #pragma unroll
        for (int f = 0; f < 8; ++f) acc[f] = (f32x4){0.f, 0.f, 0.f, 0.f};

        #pragma unroll
        for (int f = 0; f < 8; ++f) {
            #pragma unroll
            for (int ks = 0; ks < KS; ++ks) {
                bf16x8 b = *(const bf16x8*)(bbase +
                    ((size_t)((t * 8 + f) * KS + ks) << 9));
                acc[f] = __builtin_amdgcn_mfma_f32_16x16x32_bf16(a[ks], b, acc[f], 0, 0, 0);
            }
        }

        bool isL = (t < NT / 2);
        int cb = (isL ? t : (t - NT / 2)) * 128;
        unsigned short* Y = isL ? Yl : Yr;
        #pragma unroll
        for (int f = 0; f < 8; ++f) {
            #pragma unroll
            for (int r = 0; r < 4; ++r) {
                int row = row0 + wid * 16 + lg * 4 + r;
                if (row < NN) Y[(size_t)row * Mh + cb + f * 16 + lr] = f2bf(acc[f][r]);
            }
        }
    }
}

// ---------------- GAT layer 1: 4-edge unrolled online softmax ----------------
#define GAT1_EDGE(SRC, MV, P)                                               \
    {                                                                       \
        MV = *(const ushort4*)(xl + (size_t)(SRC) * 256 + c0);              \
        float e0 = bf2f(MV.x) + xr0; e0 = e0 > 0.f ? e0 : 0.2f * e0;        \
        float e1 = bf2f(MV.y) + xr1; e1 = e1 > 0.f ? e1 : 0.2f * e1;        \
        float e2 = bf2f(MV.z) + xr2; e2 = e2 > 0.f ? e2 : 0.2f * e2;        \
        float e3 = bf2f(MV.w) + xr3; e3 = e3 > 0.f ? e3 : 0.2f * e3;        \
        P = e0 * a4.x + e1 * a4.y + e2 * a4.z + e3 * a4.w;                  \
        P += __shfl_xor(P, 1);                                              \
        P += __shfl_xor(P, 2);                                              \
        P += __shfl_xor(P, 4);                                              \
    }

__global__ __launch_bounds__(256) void k_gat1(const unsigned short* __restrict__ xl,
                                              const unsigned short* __restrict__ xr,
                                              const float* __restrict__ att,
                                              const float* __restrict__ bias,
                                              const int* __restrict__ rowptr,
                                              const int* __restrict__ col,
                                              unsigned short* __restrict__ hout) {
    int wv = blockIdx.x * 4 + (threadIdx.x >> 6);
    if (wv >= NN) return;
    int lane = threadIdx.x & 63;
    int c0 = lane * 4;

    ushort4 xrv = *(const ushort4*)(xr + (size_t)wv * 256 + c0);
    float xr0 = bf2f(xrv.x), xr1 = bf2f(xrv.y), xr2 = bf2f(xrv.z), xr3 = bf2f(xrv.w);
    float4 a4 = *(const float4*)(att + c0);

    // self loop initializes running state
    ushort4 mvS; float pS;
    GAT1_EDGE(wv, mvS, pS);
    float mrun = pS, lrun = 1.f;
    float4 acc = make_float4(bf2f(mvS.x), bf2f(mvS.y), bf2f(mvS.z), bf2f(mvS.w));

    int beg = rowptr[wv], end = rowptr[wv + 1];
    int idx = beg;
    for (; idx + 4 <= end; idx += 4) {
        int s0 = col[idx], s1 = col[idx + 1], s2 = col[idx + 2], s3 = col[idx + 3];
        ushort4 mv0, mv1, mv2, mv3;
        float p0, p1, p2, p3;
        GAT1_EDGE(s0, mv0, p0);
        GAT1_EDGE(s1, mv1, p1);
        GAT1_EDGE(s2, mv2, p2);
        GAT1_EDGE(s3, mv3, p3);
        float nm = fmaxf(fmaxf(fmaxf(p0, p1), fmaxf(p2, p3)), mrun);
        float sc = __expf(mrun - nm);
        float w0 = __expf(p0 - nm), w1 = __expf(p1 - nm);
        float w2 = __expf(p2 - nm), w3 = __expf(p3 - nm);
        acc.x = acc.x * sc + bf2f(mv0.x) * w0 + bf2f(mv1.x) * w1 + bf2f(mv2.x) * w2 + bf2f(mv3.x) * w3;
        acc.y = acc.y * sc + bf2f(mv0.y) * w0 + bf2f(mv1.y) * w1 + bf2f(mv2.y) * w2 + bf2f(mv3.y) * w3;
        acc.z = acc.z * sc + bf2f(mv0.z) * w0 + bf2f(mv1.z) * w1 + bf2f(mv2.z) * w2 + bf2f(mv3.z) * w3;
        acc.w = acc.w * sc + bf2f(mv0.w) * w0 + bf2f(mv1.w) * w1 + bf2f(mv2.w) * w2 + bf2f(mv3.w) * w3;
        lrun = lrun * sc + w0 + w1 + w2 + w3;
        mrun = nm;
    }
    for (; idx < end; ++idx) {
        int src = col[idx];
        ushort4 mv; float p;
        GAT1_EDGE(src, mv, p);
        float nm = fmaxf(mrun, p);
        float sc = __expf(mrun - nm);
        float w = __expf(p - nm);
        acc.x = acc.x * sc + bf2f(mv.x) * w;
        acc.y = acc.y * sc + bf2f(mv.y) * w;
        acc.z = acc.z * sc + bf2f(mv.z) * w;
        acc.w = acc.w * sc + bf2f(mv.w) * w;
        lrun = lrun * sc + w;
        mrun = nm;
    }

    float inv = 1.f / lrun;
    float4 b4 = *(const float4*)(bias + c0);
    float ox = acc.x * inv + b4.x; ox = ox > 0.f ? ox : (__expf(ox) - 1.f);  // ELU
    float oy = acc.y * inv + b4.y; oy = oy > 0.f ? oy : (__expf(oy) - 1.f);
    float oz = acc.z * inv + b4.z; oz = oz > 0.f ? oz : (__expf(oz) - 1.f);
    float ow = acc.w * inv + b4.w; ow = ow > 0.f ? ow : (__expf(ow) - 1.f);
    *(ushort4*)(hout + (size_t)wv * 256 + c0) =
        make_ushort4(f2bf(ox), f2bf(oy), f2bf(oz), f2bf(ow));
}

// ---------------- GAT layer 2 + log_softmax: 4-edge unrolled ----------------
#define GAT2_EDGE(SRC, MV, P)                                               \
    {                                                                       \
        MV = *(const ushort2*)(xl + (size_t)(SRC) * 128 + c0);              \
        float e0 = bf2f(MV.x) + xr0; e0 = e0 > 0.f ? e0 : 0.2f * e0;        \
        float e1 = bf2f(MV.y) + xr1; e1 = e1 > 0.f ? e1 : 0.2f * e1;        \
        P = e0 * a2.x + e1 * a2.y;                                          \
        P += __shfl_xor(P, 1);                                              \
        P += __shfl_xor(P, 2);                                              \
        P += __shfl_xor(P, 4);                                              \
    }

__global__ __launch_bounds__(256) void k_gat2(const unsigned short* __restrict__ xl,
                                              const unsigned short* __restrict__ xr,
                                              const float* __restrict__ att,
                                              const float* __restrict__ bias,
                                              const int* __restrict__ rowptr,
                                              const int* __restrict__ col,
                                              float* __restrict__ out) {
    int wv = blockIdx.x * 4 + (threadIdx.x >> 6);
    if (wv >= NN) return;
    int lane = threadIdx.x & 63;
    int c0 = lane * 2;

    ushort2 xrv = *(const ushort2*)(xr + (size_t)wv * 128 + c0);
    float xr0 = bf2f(xrv.x), xr1 = bf2f(xrv.y);
    float2 a2 = *(const float2*)(att + c0);

    ushort2 mvS; float pS;
    GAT2_EDGE(wv, mvS, pS);
    float mrun = pS, lrun = 1.f;
    float ax = bf2f(mvS.x), ay = bf2f(mvS.y);

    int beg = rowptr[wv], end = rowptr[wv + 1];
    int idx = beg;
    for (; idx + 4 <= end; idx += 4) {
        int s0 = col[idx], s1 = col[idx + 1], s2 = col[idx + 2], s3 = col[idx + 3];
        ushort2 mv0, mv1, mv2, mv3;
        float p0, p1, p2, p3;
        GAT2_EDGE(s0, mv0, p0);
        GAT2_EDGE(s1, mv1, p1);
        GAT2_EDGE(s2, mv2, p2);
        GAT2_EDGE(s3, mv3, p3);
        float nm = fmaxf(fmaxf(fmaxf(p0, p1), fmaxf(p2, p3)), mrun);
        float sc = __expf(mrun - nm);
        float w0 = __expf(p0 - nm), w1 = __expf(p1 - nm);
        float w2 = __expf(p2 - nm), w3 = __expf(p3 - nm);
        ax = ax * sc + bf2f(mv0.x) * w0 + bf2f(mv1.x) * w1 + bf2f(mv2.x) * w2 + bf2f(mv3.x) * w3;
        ay = ay * sc + bf2f(mv0.y) * w0 + bf2f(mv1.y) * w1 + bf2f(mv2.y) * w2 + bf2f(mv3.y) * w3;
        lrun = lrun * sc + w0 + w1 + w2 + w3;
        mrun = nm;
    }
    for (; idx < end; ++idx) {
        int src = col[idx];
        ushort2 mv; float p;
        GAT2_EDGE(src, mv, p);
        float nm = fmaxf(mrun, p);
        float sc = __expf(mrun - nm);
        float w = __expf(p - nm);
        ax = ax * sc + bf2f(mv.x) * w;
        ay = ay * sc + bf2f(mv.y) * w;
        lrun = lrun * sc + w;
        mrun = nm;
    }

    float inv = 1.f / lrun;
    float ox = ax * inv + bias[c0];
    float oy = ay * inv + bias[c0 + 1];

    float mx = fmaxf(ox, oy);
    #pragma unroll
    for (int off = 1; off < 64; off <<= 1) mx = fmaxf(mx, __shfl_xor(mx, off));
    float se = __expf(ox - mx) + __expf(oy - mx);
    #pragma unroll
    for (int off = 1; off < 64; off <<= 1) se += __shfl_xor(se, off);
    float lse = mx + logf(se);

    out[(size_t)wv * 128 + c0] = ox - lse;
    out[(size_t)wv * 128 + c0 + 1] = oy - lse;
}

// ---------------- launch ----------------
extern "C" void kernel_launch(void* const* d_in, const int* in_sizes, int n_in,
                              void* d_out, int out_size, void* d_ws, size_t ws_size,
                              hipStream_t stream) {
    const float* x    = (const float*)d_in[0];
    const int*   ei   = (const int*)d_in[1];
    const float* W1l  = (const float*)d_in[2];
    const float* W1r  = (const float*)d_in[3];
    const float* att1 = (const float*)d_in[4];
    const float* b1   = (const float*)d_in[5];
    const float* W2l  = (const float*)d_in[6];
    const float* W2r  = (const float*)d_in[7];
    const float* att2 = (const float*)d_in[8];
    const float* b2   = (const float*)d_in[9];
    float* out = (float*)d_out;

    char* p = (char*)d_ws;
    auto alloc = [&](size_t bytes) {
        char* r = p;
        p += (bytes + 255) & ~(size_t)255;
        return r;
    };
    int* deg      = (int*)alloc((size_t)NN * 4);
    int* rowptr   = (int*)alloc((size_t)(NN + 1) * 4);
    int* bsum     = (int*)alloc((size_t)NB * 4);
    int* cursor   = (int*)alloc((size_t)NN * 4);
    int* col      = (int*)alloc((size_t)NE * 4);
    unsigned short* xb   = (unsigned short*)alloc((size_t)NN * 128 * 2);
    unsigned short* Wp1  = (unsigned short*)alloc((size_t)65536 * 2);
    unsigned short* Wp2  = (unsigned short*)alloc((size_t)65536 * 2);
    unsigned short* xl1b = (unsigned short*)alloc((size_t)NN * 256 * 2);
    unsigned short* xr1b = (unsigned short*)alloc((size_t)NN * 256 * 2);
    unsigned short* h1b  = (unsigned short*)alloc((size_t)NN * 256 * 2);
    unsigned short* xl2b = (unsigned short*)alloc((size_t)NN * 128 * 2);
    unsigned short* xr2b = (unsigned short*)alloc((size_t)NN * 128 * 2);

    hipMemsetAsync(deg, 0, (size_t)NN * 4, stream);
    int egrid = (NE + 255) / 256;
    k_hist<<<egrid, 256, 0, stream>>>(ei, deg);
    k_scan_block<<<NB, 256, 0, stream>>>(deg, rowptr, bsum);
    k_scan_top<<<1, 256, 0, stream>>>(bsum);
    k_scan_add<<<NB, 256, 0, stream>>>(rowptr, bsum, cursor);
    k_scatter<<<egrid, 256, 0, stream>>>(ei, cursor, col);

    // prep
    int n4 = NN * 128 / 4;
    k_cvt_x<<<(n4 + 255) / 256, 256, 0, stream>>>(x, xb, n4);
    k_prep_w<128, 256, 4><<<256, 256, 0, stream>>>(W1l, W1r, Wp1);
    k_prep_w<256, 128, 2><<<256, 256, 0, stream>>>(W2l, W2r, Wp2);

    int rblk = (NN + 63) / 64;  // 782
    k_gemm_mfma<128, 4><<<rblk, 256, 0, stream>>>(xb, Wp1, xl1b, xr1b, 256);
    k_gat1<<<(NN + 3) / 4, 256, 0, stream>>>(xl1b, xr1b, att1, b1, rowptr, col, h1b);
    k_gemm_mfma<256, 2><<<rblk, 256, 0, stream>>>(h1b, Wp2, xl2b, xr2b, 128);
    k_gat2<<<(NN + 3) / 4, 256, 0, stream>>>(xl2b, xr2b, att2, b2, rowptr, col, out);
}

// Round 13
// 314.125 us; speedup vs baseline: 1.8793x; 1.0186x over previous
//
#include <hip/hip_runtime.h>
#include <math.h>

// GATv2 2-layer: N=50000, E=600000, heads=8, C1=32, C2=16.
// CSR build -> prep (x->bf16, W->MFMA-fragment-packed bf16) -> MFMA GEMM1 ->
// GAT1(+ELU) -> MFMA GEMM2 -> GAT2(+log_softmax).
// GAT gathers use 32-bit byte offsets (saddr-form loads) + dword bf16 unpack.
constexpr int NN = 50000;
constexpr int NE = 600000;
constexpr int NB = (NN + 255) / 256;

typedef __bf16 bf16x8 __attribute__((ext_vector_type(8)));
typedef float f32x4 __attribute__((ext_vector_type(4)));

__device__ inline unsigned short f2bf(float f) {
    unsigned int u = __float_as_uint(f);
    u += 0x7fffu + ((u >> 16) & 1u);   // RNE
    return (unsigned short)(u >> 16);
}
__device__ inline float bf2f(unsigned short s) {
    return __uint_as_float((unsigned int)s << 16);
}

// ---------------- CSR build ----------------
__global__ __launch_bounds__(256) void k_hist(const int* __restrict__ ei,
                                              int* __restrict__ deg) {
    int e = blockIdx.x * 256 + threadIdx.x;
    if (e < NE) atomicAdd(&deg[ei[NE + e]], 1);
}

__global__ __launch_bounds__(256) void k_scan_block(const int* __restrict__ deg,
                                                    int* __restrict__ rowptr,
                                                    int* __restrict__ bsum) {
    __shared__ int s[256];
    int tid = threadIdx.x;
    int i = blockIdx.x * 256 + tid;
    int v = (i < NN) ? deg[i] : 0;
    s[tid] = v;
    __syncthreads();
    #pragma unroll
    for (int off = 1; off < 256; off <<= 1) {
        int t = (tid >= off) ? s[tid - off] : 0;
        __syncthreads();
        s[tid] += t;
        __syncthreads();
    }
    if (i < NN) rowptr[i] = s[tid] - v;
    if (tid == 255) bsum[blockIdx.x] = s[255];
}

__global__ __launch_bounds__(256) void k_scan_top(int* __restrict__ bsum) {
    __shared__ int s[256];
    int tid = threadIdx.x;
    int v = (tid < NB) ? bsum[tid] : 0;
    s[tid] = v;
    __syncthreads();
    #pragma unroll
    for (int off = 1; off < 256; off <<= 1) {
        int t = (tid >= off) ? s[tid - off] : 0;
        __syncthreads();
        s[tid] += t;
        __syncthreads();
    }
    if (tid < NB) bsum[tid] = s[tid] - v;
}

__global__ __launch_bounds__(256) void k_scan_add(int* __restrict__ rowptr,
                                                  const int* __restrict__ bsum,
                                                  int* __restrict__ cursor) {
    int i = blockIdx.x * 256 + threadIdx.x;
    if (i < NN) {
        int r = rowptr[i] + bsum[blockIdx.x];
        rowptr[i] = r;
        cursor[i] = r;
    }
    if (i == 0) rowptr[NN] = NE;
}

__global__ __launch_bounds__(256) void k_scatter(const int* __restrict__ ei,
                                                 int* __restrict__ cursor,
                                                 int* __restrict__ col) {
    int e = blockIdx.x * 256 + threadIdx.x;
    if (e < NE) {
        int s = ei[e];
        int d = ei[NE + e];
        int p = atomicAdd(&cursor[d], 1);
        col[p] = s;
    }
}

// ---------------- prep ----------------
__global__ __launch_bounds__(256) void k_cvt_x(const float* __restrict__ x,
                                               unsigned short* __restrict__ xb,
                                               int n4) {
    int i = blockIdx.x * 256 + threadIdx.x;
    if (i < n4) {
        float4 v = *(const float4*)(x + (size_t)i * 4);
        *(ushort4*)(xb + (size_t)i * 4) =
            make_ushort4(f2bf(v.x), f2bf(v.y), f2bf(v.z), f2bf(v.w));
    }
}

// Pack W into MFMA-fragment order:
// Wp[ (((t*8+f)*KS+ks)*64 + l)*8 + j ] = B[k=ks*32+(l>>4)*8+j][c=t*128+f*16+(l&15)]
template <int K, int M, int NT>
__global__ __launch_bounds__(256) void k_prep_w(const float* __restrict__ Wl,
                                                const float* __restrict__ Wr,
                                                unsigned short* __restrict__ Wp) {
    constexpr int KS = K / 32;
    int i = blockIdx.x * 256 + threadIdx.x;
    if (i >= NT * 8 * KS * 512) return;
    int idx = i;
    int j = idx & 7; idx >>= 3;
    int l = idx & 63; idx >>= 6;
    int ks = idx % KS; idx /= KS;
    int f = idx & 7; idx >>= 3;
    int t = idx;
    int k = ks * 32 + (l >> 4) * 8 + j;
    int c = t * 128 + f * 16 + (l & 15);
    float v = (c < M) ? Wl[(size_t)k * M + c] : Wr[(size_t)k * M + (c - M)];
    Wp[i] = f2bf(v);
}

// ---------------- MFMA bf16 dual GEMM ----------------
template <int K, int NT>
__global__ __launch_bounds__(256) void k_gemm_mfma(
        const unsigned short* __restrict__ Xb,
        const unsigned short* __restrict__ Wp,
        unsigned short* __restrict__ Yl,
        unsigned short* __restrict__ Yr,
        int Mh) {
    constexpr int KS = K / 32;
    constexpr int KP = K + 8;
    __shared__ unsigned short As[64 * KP];

    int tid = threadIdx.x;
    int row0 = blockIdx.x * 64;

    for (int i = tid; i < 64 * K / 4; i += 256) {
        int idx = i * 4;
        int r = idx / K, c = idx - r * K;
        int gr = row0 + r;
        ushort4 v = make_ushort4(0, 0, 0, 0);
        if (gr < NN) v = *(const ushort4*)(Xb + (size_t)gr * K + c);
        *(ushort4*)&As[r * KP + c] = v;
    }
    __syncthreads();

    int wid = tid >> 6, lane = tid & 63;
    int lr = lane & 15, lg = lane >> 4;
    const unsigned short* ap = As + (wid * 16 + lr) * KP + lg * 8;

    bf16x8 a[KS];
    #pragma unroll
    for (int ks = 0; ks < KS; ++ks) a[ks] = *(const bf16x8*)(ap + ks * 32);

    const unsigned short* bbase = Wp + (size_t)lane * 8;

    for (int t = 0; t < NT; ++t) {
        f32x4 acc[8];
        #pragma unroll
        for (int f = 0; f < 8; ++f) acc[f] = (f32x4){0.f, 0.f, 0.f, 0.f};

        #pragma unroll
        for (int f = 0; f < 8; ++f) {
            #pragma unroll
            for (int ks = 0; ks < KS; ++ks) {
                bf16x8 b = *(const bf16x8*)(bbase +
                    ((size_t)((t * 8 + f) * KS + ks) << 9));
                acc[f] = __builtin_amdgcn_mfma_f32_16x16x32_bf16(a[ks], b, acc[f], 0, 0, 0);
            }
        }

        bool isL = (t < NT / 2);
        int cb = (isL ? t : (t - NT / 2)) * 128;
        unsigned short* Y = isL ? Yl : Yr;
        #pragma unroll
        for (int f = 0; f < 8; ++f) {
            #pragma unroll
            for (int r = 0; r < 4; ++r) {
                int row = row0 + wid * 16 + lg * 4 + r;
                if (row < NN) Y[(size_t)row * Mh + cb + f * 16 + lr] = f2bf(acc[f][r]);
            }
        }
    }
}

// ---------------- GAT layer 1: 4-edge unroll, 32-bit-offset gathers ----------
// row = 512 B (256 bf16). Outputs raw message m0..m3 + head logit P.
#define GAT1_EDGE(SRC, M0, M1, M2, M3, P)                                   \
    {                                                                       \
        uint2 u = *(const uint2*)(xlb + (((unsigned)(SRC)) << 9) + boff);   \
        M0 = __uint_as_float(u.x << 16);                                    \
        M1 = __uint_as_float(u.x & 0xffff0000u);                            \
        M2 = __uint_as_float(u.y << 16);                                    \
        M3 = __uint_as_float(u.y & 0xffff0000u);                            \
        float e0 = M0 + xr0, e1 = M1 + xr1, e2 = M2 + xr2, e3 = M3 + xr3;   \
        e0 = fmaxf(e0, 0.2f * e0); e1 = fmaxf(e1, 0.2f * e1);               \
        e2 = fmaxf(e2, 0.2f * e2); e3 = fmaxf(e3, 0.2f * e3);               \
        P = e0 * a4.x + e1 * a4.y + e2 * a4.z + e3 * a4.w;                  \
        P += __shfl_xor(P, 1);                                              \
        P += __shfl_xor(P, 2);                                              \
        P += __shfl_xor(P, 4);                                              \
    }

__global__ __launch_bounds__(256) void k_gat1(const unsigned short* __restrict__ xl,
                                              const unsigned short* __restrict__ xr,
                                              const float* __restrict__ att,
                                              const float* __restrict__ bias,
                                              const int* __restrict__ rowptr,
                                              const int* __restrict__ col,
                                              unsigned short* __restrict__ hout) {
    int wv = blockIdx.x * 4 + (threadIdx.x >> 6);
    if (wv >= NN) return;
    int lane = threadIdx.x & 63;
    int c0 = lane * 4;
    const char* xlb = (const char*)xl;
    unsigned boff = (unsigned)c0 * 2;

    ushort4 xrv = *(const ushort4*)(xr + (size_t)wv * 256 + c0);
    float xr0 = bf2f(xrv.x), xr1 = bf2f(xrv.y), xr2 = bf2f(xrv.z), xr3 = bf2f(xrv.w);
    float4 a4 = *(const float4*)(att + c0);

    // self loop initializes running state
    float sm0, sm1, sm2, sm3, pS;
    GAT1_EDGE(wv, sm0, sm1, sm2, sm3, pS);
    float mrun = pS, lrun = 1.f;
    float4 acc = make_float4(sm0, sm1, sm2, sm3);

    int beg = rowptr[wv], end = rowptr[wv + 1];
    int idx = beg;
    for (; idx + 4 <= end; idx += 4) {
        int s0 = col[idx], s1 = col[idx + 1], s2 = col[idx + 2], s3 = col[idx + 3];
        float m00, m01, m02, m03, p0;
        float m10, m11, m12, m13, p1;
        float m20, m21, m22, m23, p2;
        float m30, m31, m32, m33, p3;
        GAT1_EDGE(s0, m00, m01, m02, m03, p0);
        GAT1_EDGE(s1, m10, m11, m12, m13, p1);
        GAT1_EDGE(s2, m20, m21, m22, m23, p2);
        GAT1_EDGE(s3, m30, m31, m32, m33, p3);
        float nm = fmaxf(fmaxf(fmaxf(p0, p1), fmaxf(p2, p3)), mrun);
        float sc = __expf(mrun - nm);
        float w0 = __expf(p0 - nm), w1 = __expf(p1 - nm);
        float w2 = __expf(p2 - nm), w3 = __expf(p3 - nm);
        acc.x = acc.x * sc + m00 * w0 + m10 * w1 + m20 * w2 + m30 * w3;
        acc.y = acc.y * sc + m01 * w0 + m11 * w1 + m21 * w2 + m31 * w3;
        acc.z = acc.z * sc + m02 * w0 + m12 * w1 + m22 * w2 + m32 * w3;
        acc.w = acc.w * sc + m03 * w0 + m13 * w1 + m23 * w2 + m33 * w3;
        lrun = lrun * sc + w0 + w1 + w2 + w3;
        mrun = nm;
    }
    for (; idx < end; ++idx) {
        int src = col[idx];
        float m0, m1, m2, m3, p;
        GAT1_EDGE(src, m0, m1, m2, m3, p);
        float nm = fmaxf(mrun, p);
        float sc = __expf(mrun - nm);
        float w = __expf(p - nm);
        acc.x = acc.x * sc + m0 * w;
        acc.y = acc.y * sc + m1 * w;
        acc.z = acc.z * sc + m2 * w;
        acc.w = acc.w * sc + m3 * w;
        lrun = lrun * sc + w;
        mrun = nm;
    }

    float inv = 1.f / lrun;
    float4 b4 = *(const float4*)(bias + c0);
    float ox = acc.x * inv + b4.x; ox = ox > 0.f ? ox : (__expf(ox) - 1.f);  // ELU
    float oy = acc.y * inv + b4.y; oy = oy > 0.f ? oy : (__expf(oy) - 1.f);
    float oz = acc.z * inv + b4.z; oz = oz > 0.f ? oz : (__expf(oz) - 1.f);
    float ow = acc.w * inv + b4.w; ow = ow > 0.f ? ow : (__expf(ow) - 1.f);
    *(ushort4*)(hout + (size_t)wv * 256 + c0) =
        make_ushort4(f2bf(ox), f2bf(oy), f2bf(oz), f2bf(ow));
}

// ---------------- GAT layer 2 + log_softmax: 4-edge unroll ----------------
// row = 256 B (128 bf16).
#define GAT2_EDGE(SRC, M0, M1, P)                                           \
    {                                                                       \
        unsigned u = *(const unsigned*)(xlb + (((unsigned)(SRC)) << 8) + boff); \
        M0 = __uint_as_float(u << 16);                                      \
        M1 = __uint_as_float(u & 0xffff0000u);                              \
        float e0 = M0 + xr0, e1 = M1 + xr1;                                 \
        e0 = fmaxf(e0, 0.2f * e0); e1 = fmaxf(e1, 0.2f * e1);               \
        P = e0 * a2.x + e1 * a2.y;                                          \
        P += __shfl_xor(P, 1);                                              \
        P += __shfl_xor(P, 2);                                              \
        P += __shfl_xor(P, 4);                                              \
    }

__global__ __launch_bounds__(256) void k_gat2(const unsigned short* __restrict__ xl,
                                              const unsigned short* __restrict__ xr,
                                              const float* __restrict__ att,
                                              const float* __restrict__ bias,
                                              const int* __restrict__ rowptr,
                                              const int* __restrict__ col,
                                              float* __restrict__ out) {
    int wv = blockIdx.x * 4 + (threadIdx.x >> 6);
    if (wv >= NN) return;
    int lane = threadIdx.x & 63;
    int c0 = lane * 2;
    const char* xlb = (const char*)xl;
    unsigned boff = (unsigned)c0 * 2;

    ushort2 xrv = *(const ushort2*)(xr + (size_t)wv * 128 + c0);
    float xr0 = bf2f(xrv.x), xr1 = bf2f(xrv.y);
    float2 a2 = *(const float2*)(att + c0);

    float sa, sb, pS;
    GAT2_EDGE(wv, sa, sb, pS);
    float mrun = pS, lrun = 1.f;
    float ax = sa, ay = sb;

    int beg = rowptr[wv], end = rowptr[wv + 1];
    int idx = beg;
    for (; idx + 4 <= end; idx += 4) {
        int s0 = col[idx], s1 = col[idx + 1], s2 = col[idx + 2], s3 = col[idx + 3];
        float m00, m01, p0;
        float m10, m11, p1;
        float m20, m21, p2;
        float m30, m31, p3;
        GAT2_EDGE(s0, m00, m01, p0);
        GAT2_EDGE(s1, m10, m11, p1);
        GAT2_EDGE(s2, m20, m21, p2);
        GAT2_EDGE(s3, m30, m31, p3);
        float nm = fmaxf(fmaxf(fmaxf(p0, p1), fmaxf(p2, p3)), mrun);
        float sc = __expf(mrun - nm);
        float w0 = __expf(p0 - nm), w1 = __expf(p1 - nm);
        float w2 = __expf(p2 - nm), w3 = __expf(p3 - nm);
        ax = ax * sc + m00 * w0 + m10 * w1 + m20 * w2 + m30 * w3;
        ay = ay * sc + m01 * w0 + m11 * w1 + m21 * w2 + m31 * w3;
        lrun = lrun * sc + w0 + w1 + w2 + w3;
        mrun = nm;
    }
    for (; idx < end; ++idx) {
        int src = col[idx];
        float m0, m1, p;
        GAT2_EDGE(src, m0, m1, p);
        float nm = fmaxf(mrun, p);
        float sc = __expf(mrun - nm);
        float w = __expf(p - nm);
        ax = ax * sc + m0 * w;
        ay = ay * sc + m1 * w;
        lrun = lrun * sc + w;
        mrun = nm;
    }

    float inv = 1.f / lrun;
    float ox = ax * inv + bias[c0];
    float oy = ay * inv + bias[c0 + 1];

    float mx = fmaxf(ox, oy);
    #pragma unroll
    for (int off = 1; off < 64; off <<= 1) mx = fmaxf(mx, __shfl_xor(mx, off));
    float se = __expf(ox - mx) + __expf(oy - mx);
    #pragma unroll
    for (int off = 1; off < 64; off <<= 1) se += __shfl_xor(se, off);
    float lse = mx + logf(se);

    out[(size_t)wv * 128 + c0] = ox - lse;
    out[(size_t)wv * 128 + c0 + 1] = oy - lse;
}

// ---------------- launch ----------------
extern "C" void kernel_launch(void* const* d_in, const int* in_sizes, int n_in,
                              void* d_out, int out_size, void* d_ws, size_t ws_size,
                              hipStream_t stream) {
    const float* x    = (const float*)d_in[0];
    const int*   ei   = (const int*)d_in[1];
    const float* W1l  = (const float*)d_in[2];
    const float* W1r  = (const float*)d_in[3];
    const float* att1 = (const float*)d_in[4];
    const float* b1   = (const float*)d_in[5];
    const float* W2l  = (const float*)d_in[6];
    const float* W2r  = (const float*)d_in[7];
    const float* att2 = (const float*)d_in[8];
    const float* b2   = (const float*)d_in[9];
    float* out = (float*)d_out;

    char* p = (char*)d_ws;
    auto alloc = [&](size_t bytes) {
        char* r = p;
        p += (bytes + 255) & ~(size_t)255;
        return r;
    };
    int* deg      = (int*)alloc((size_t)NN * 4);
    int* rowptr   = (int*)alloc((size_t)(NN + 1) * 4);
    int* bsum     = (int*)alloc((size_t)NB * 4);
    int* cursor   = (int*)alloc((size_t)NN * 4);
    int* col      = (int*)alloc((size_t)NE * 4);
    unsigned short* xb   = (unsigned short*)alloc((size_t)NN * 128 * 2);
    unsigned short* Wp1  = (unsigned short*)alloc((size_t)65536 * 2);
    unsigned short* Wp2  = (unsigned short*)alloc((size_t)65536 * 2);
    unsigned short* xl1b = (unsigned short*)alloc((size_t)NN * 256 * 2);
    unsigned short* xr1b = (unsigned short*)alloc((size_t)NN * 256 * 2);
    unsigned short* h1b  = (unsigned short*)alloc((size_t)NN * 256 * 2);
    unsigned short* xl2b = (unsigned short*)alloc((size_t)NN * 128 * 2);
    unsigned short* xr2b = (unsigned short*)alloc((size_t)NN * 128 * 2);

    hipMemsetAsync(deg, 0, (size_t)NN * 4, stream);
    int egrid = (NE + 255) / 256;
    k_hist<<<egrid, 256, 0, stream>>>(ei, deg);
    k_scan_block<<<NB, 256, 0, stream>>>(deg, rowptr, bsum);
    k_scan_top<<<1, 256, 0, stream>>>(bsum);
    k_scan_add<<<NB, 256, 0, stream>>>(rowptr, bsum, cursor);
    k_scatter<<<egrid, 256, 0, stream>>>(ei, cursor, col);

    // prep
    int n4 = NN * 128 / 4;
    k_cvt_x<<<(n4 + 255) / 256, 256, 0, stream>>>(x, xb, n4);
    k_prep_w<128, 256, 4><<<256, 256, 0, stream>>>(W1l, W1r, Wp1);
    k_prep_w<256, 128, 2><<<256, 256, 0, stream>>>(W2l, W2r, Wp2);

    int rblk = (NN + 63) / 64;  // 782
    k_gemm_mfma<128, 4><<<rblk, 256, 0, stream>>>(xb, Wp1, xl1b, xr1b, 256);
    k_gat1<<<(NN + 3) / 4, 256, 0, stream>>>(xl1b, xr1b, att1, b1, rowptr, col, h1b);
    k_gemm_mfma<256, 2><<<rblk, 256, 0, stream>>>(h1b, Wp2, xl2b, xr2b, 128);
    k_gat2<<<(NN + 3) / 4, 256, 0, stream>>>(xl2b, xr2b, att2, b2, rowptr, col, out);
}

// Round 14
// 311.498 us; speedup vs baseline: 1.8952x; 1.0084x over previous
//
#include <hip/hip_runtime.h>
#include <math.h>

// GATv2 2-layer: N=50000, E=600000, heads=8, C1=32, C2=16.
// CSR build -> prep (W->MFMA-fragment-packed bf16) -> MFMA GEMM1 (fused f32->bf16)
// -> GAT1(+ELU) -> MFMA GEMM2 -> GAT2(+log_softmax).
// GAT edge math on f32x2 ext-vectors -> v_pk_* packed fp32 (2x VALU rate).
constexpr int NN = 50000;
constexpr int NE = 600000;
constexpr int NB = (NN + 255) / 256;

typedef __bf16 bf16x8 __attribute__((ext_vector_type(8)));
typedef float f32x4 __attribute__((ext_vector_type(4)));
typedef float f32x2 __attribute__((ext_vector_type(2)));

__device__ inline unsigned short f2bf(float f) {
    unsigned int u = __float_as_uint(f);
    u += 0x7fffu + ((u >> 16) & 1u);   // RNE
    return (unsigned short)(u >> 16);
}
__device__ inline float bf2f(unsigned short s) {
    return __uint_as_float((unsigned int)s << 16);
}

// ---------------- CSR build ----------------
__global__ __launch_bounds__(256) void k_hist(const int* __restrict__ ei,
                                              int* __restrict__ deg) {
    int e = blockIdx.x * 256 + threadIdx.x;
    if (e < NE) atomicAdd(&deg[ei[NE + e]], 1);
}

__global__ __launch_bounds__(256) void k_scan_block(const int* __restrict__ deg,
                                                    int* __restrict__ rowptr,
                                                    int* __restrict__ bsum) {
    __shared__ int s[256];
    int tid = threadIdx.x;
    int i = blockIdx.x * 256 + tid;
    int v = (i < NN) ? deg[i] : 0;
    s[tid] = v;
    __syncthreads();
    #pragma unroll
    for (int off = 1; off < 256; off <<= 1) {
        int t = (tid >= off) ? s[tid - off] : 0;
        __syncthreads();
        s[tid] += t;
        __syncthreads();
    }
    if (i < NN) rowptr[i] = s[tid] - v;
    if (tid == 255) bsum[blockIdx.x] = s[255];
}

__global__ __launch_bounds__(256) void k_scan_top(int* __restrict__ bsum) {
    __shared__ int s[256];
    int tid = threadIdx.x;
    int v = (tid < NB) ? bsum[tid] : 0;
    s[tid] = v;
    __syncthreads();
    #pragma unroll
    for (int off = 1; off < 256; off <<= 1) {
        int t = (tid >= off) ? s[tid - off] : 0;
        __syncthreads();
        s[tid] += t;
        __syncthreads();
    }
    if (tid < NB) bsum[tid] = s[tid] - v;
}

__global__ __launch_bounds__(256) void k_scan_add(int* __restrict__ rowptr,
                                                  const int* __restrict__ bsum,
                                                  int* __restrict__ cursor) {
    int i = blockIdx.x * 256 + threadIdx.x;
    if (i < NN) {
        int r = rowptr[i] + bsum[blockIdx.x];
        rowptr[i] = r;
        cursor[i] = r;
    }
    if (i == 0) rowptr[NN] = NE;
}

__global__ __launch_bounds__(256) void k_scatter(const int* __restrict__ ei,
                                                 int* __restrict__ cursor,
                                                 int* __restrict__ col) {
    int e = blockIdx.x * 256 + threadIdx.x;
    if (e < NE) {
        int s = ei[e];
        int d = ei[NE + e];
        int p = atomicAdd(&cursor[d], 1);
        col[p] = s;
    }
}

// ---------------- prep ----------------
// Pack W into MFMA-fragment order:
// Wp[ (((t*8+f)*KS+ks)*64 + l)*8 + j ] = B[k=ks*32+(l>>4)*8+j][c=t*128+f*16+(l&15)]
template <int K, int M, int NT>
__global__ __launch_bounds__(256) void k_prep_w(const float* __restrict__ Wl,
                                                const float* __restrict__ Wr,
                                                unsigned short* __restrict__ Wp) {
    constexpr int KS = K / 32;
    int i = blockIdx.x * 256 + threadIdx.x;
    if (i >= NT * 8 * KS * 512) return;
    int idx = i;
    int j = idx & 7; idx >>= 3;
    int l = idx & 63; idx >>= 6;
    int ks = idx % KS; idx /= KS;
    int f = idx & 7; idx >>= 3;
    int t = idx;
    int k = ks * 32 + (l >> 4) * 8 + j;
    int c = t * 128 + f * 16 + (l & 15);
    float v = (c < M) ? Wl[(size_t)k * M + c] : Wr[(size_t)k * M + (c - M)];
    Wp[i] = f2bf(v);
}

// ---------------- MFMA bf16 dual GEMM ----------------
// CVT: input is f32 (convert during staging); else bf16-as-ushort.
template <int K, int NT, bool CVT>
__global__ __launch_bounds__(256) void k_gemm_mfma(
        const void* __restrict__ Xin,
        const unsigned short* __restrict__ Wp,
        unsigned short* __restrict__ Yl,
        unsigned short* __restrict__ Yr,
        int Mh) {
    constexpr int KS = K / 32;
    constexpr int KP = K + 8;
    __shared__ unsigned short As[64 * KP];

    int tid = threadIdx.x;
    int row0 = blockIdx.x * 64;

    for (int i = tid; i < 64 * K / 4; i += 256) {
        int idx = i * 4;
        int r = idx / K, c = idx - r * K;
        int gr = row0 + r;
        ushort4 v = make_ushort4(0, 0, 0, 0);
        if (gr < NN) {
            if constexpr (CVT) {
                float4 x4 = *(const float4*)((const float*)Xin + (size_t)gr * K + c);
                v = make_ushort4(f2bf(x4.x), f2bf(x4.y), f2bf(x4.z), f2bf(x4.w));
            } else {
                v = *(const ushort4*)((const unsigned short*)Xin + (size_t)gr * K + c);
            }
        }
        *(ushort4*)&As[r * KP + c] = v;
    }
    __syncthreads();

    int wid = tid >> 6, lane = tid & 63;
    int lr = lane & 15, lg = lane >> 4;
    const unsigned short* ap = As + (wid * 16 + lr) * KP + lg * 8;

    bf16x8 a[KS];
    #pragma unroll
    for (int ks = 0; ks < KS; ++ks) a[ks] = *(const bf16x8*)(ap + ks * 32);

    const unsigned short* bbase = Wp + (size_t)lane * 8;

    for (int t = 0; t < NT; ++t) {
        f32x4 acc[8];
        #pragma unroll
        for (int f = 0; f < 8; ++f) acc[f] = (f32x4){0.f, 0.f, 0.f, 0.f};

        #pragma unroll
        for (int f = 0; f < 8; ++f) {
            #pragma unroll
            for (int ks = 0; ks < KS; ++ks) {
                bf16x8 b = *(const bf16x8*)(bbase +
                    ((size_t)((t * 8 + f) * KS + ks) << 9));
                acc[f] = __builtin_amdgcn_mfma_f32_16x16x32_bf16(a[ks], b, acc[f], 0, 0, 0);
            }
        }

        bool isL = (t < NT / 2);
        int cb = (isL ? t : (t - NT / 2)) * 128;
        unsigned short* Y = isL ? Yl : Yr;
        #pragma unroll
        for (int f = 0; f < 8; ++f) {
            #pragma unroll
            for (int r = 0; r < 4; ++r) {
                int row = row0 + wid * 16 + lg * 4 + r;
                if (row < NN) Y[(size_t)row * Mh + cb + f * 16 + lr] = f2bf(acc[f][r]);
            }
        }
    }
}

// ---------------- GAT layer 1: f32x2 packed edge math ----------------
// row = 512 B (256 bf16). MA/MB are f32x2 message pairs, P the head logit.
#define GAT1_EDGE(SRC, MA, MB, P)                                           \
    {                                                                       \
        uint2 u = *(const uint2*)(xlb + (((unsigned)(SRC)) << 9) + boff);   \
        MA = (f32x2){__uint_as_float(u.x << 16),                            \
                     __uint_as_float(u.x & 0xffff0000u)};                   \
        MB = (f32x2){__uint_as_float(u.y << 16),                            \
                     __uint_as_float(u.y & 0xffff0000u)};                   \
        f32x2 ea = MA + xra, eb = MB + xrb;                                 \
        ea = __builtin_elementwise_max(ea, 0.2f * ea);                      \
        eb = __builtin_elementwise_max(eb, 0.2f * eb);                      \
        f32x2 pp = ea * aa + eb * ab;                                       \
        P = pp.x + pp.y;                                                    \
        P += __shfl_xor(P, 1);                                              \
        P += __shfl_xor(P, 2);                                              \
        P += __shfl_xor(P, 4);                                              \
    }

__global__ __launch_bounds__(256) void k_gat1(const unsigned short* __restrict__ xl,
                                              const unsigned short* __restrict__ xr,
                                              const float* __restrict__ att,
                                              const float* __restrict__ bias,
                                              const int* __restrict__ rowptr,
                                              const int* __restrict__ col,
                                              unsigned short* __restrict__ hout) {
    int wv = blockIdx.x * 4 + (threadIdx.x >> 6);
    if (wv >= NN) return;
    int lane = threadIdx.x & 63;
    int c0 = lane * 4;
    const char* xlb = (const char*)xl;
    unsigned boff = (unsigned)c0 * 2;

    ushort4 xrv = *(const ushort4*)(xr + (size_t)wv * 256 + c0);
    f32x2 xra = (f32x2){bf2f(xrv.x), bf2f(xrv.y)};
    f32x2 xrb = (f32x2){bf2f(xrv.z), bf2f(xrv.w)};
    float4 a4 = *(const float4*)(att + c0);
    f32x2 aa = (f32x2){a4.x, a4.y};
    f32x2 ab = (f32x2){a4.z, a4.w};

    // self loop initializes running state
    f32x2 sa, sb; float pS;
    GAT1_EDGE(wv, sa, sb, pS);
    float mrun = pS, lrun = 1.f;
    f32x2 acca = sa, accb = sb;

    int beg = rowptr[wv], end = rowptr[wv + 1];
    int idx = beg;
    for (; idx + 4 <= end; idx += 4) {
        int s0 = col[idx], s1 = col[idx + 1], s2 = col[idx + 2], s3 = col[idx + 3];
        f32x2 ma0, mb0, ma1, mb1, ma2, mb2, ma3, mb3;
        float p0, p1, p2, p3;
        GAT1_EDGE(s0, ma0, mb0, p0);
        GAT1_EDGE(s1, ma1, mb1, p1);
        GAT1_EDGE(s2, ma2, mb2, p2);
        GAT1_EDGE(s3, ma3, mb3, p3);
        float nm = fmaxf(fmaxf(fmaxf(p0, p1), fmaxf(p2, p3)), mrun);
        float sc = __expf(mrun - nm);
        float w0 = __expf(p0 - nm), w1 = __expf(p1 - nm);
        float w2 = __expf(p2 - nm), w3 = __expf(p3 - nm);
        acca = acca * sc + ma0 * w0 + ma1 * w1 + ma2 * w2 + ma3 * w3;
        accb = accb * sc + mb0 * w0 + mb1 * w1 + mb2 * w2 + mb3 * w3;
        lrun = lrun * sc + w0 + w1 + w2 + w3;
        mrun = nm;
    }
    for (; idx < end; ++idx) {
        int src = col[idx];
        f32x2 ma, mb; float p;
        GAT1_EDGE(src, ma, mb, p);
        float nm = fmaxf(mrun, p);
        float sc = __expf(mrun - nm);
        float w = __expf(p - nm);
        acca = acca * sc + ma * w;
        accb = accb * sc + mb * w;
        lrun = lrun * sc + w;
        mrun = nm;
    }

    float inv = 1.f / lrun;
    float4 b4 = *(const float4*)(bias + c0);
    float ox = acca.x * inv + b4.x; ox = ox > 0.f ? ox : (__expf(ox) - 1.f);  // ELU
    float oy = acca.y * inv + b4.y; oy = oy > 0.f ? oy : (__expf(oy) - 1.f);
    float oz = accb.x * inv + b4.z; oz = oz > 0.f ? oz : (__expf(oz) - 1.f);
    float ow = accb.y * inv + b4.w; ow = ow > 0.f ? ow : (__expf(ow) - 1.f);
    *(ushort4*)(hout + (size_t)wv * 256 + c0) =
        make_ushort4(f2bf(ox), f2bf(oy), f2bf(oz), f2bf(ow));
}

// ---------------- GAT layer 2 + log_softmax: f32x2 packed ----------------
// row = 256 B (128 bf16).
#define GAT2_EDGE(SRC, MA, P)                                               \
    {                                                                       \
        unsigned u = *(const unsigned*)(xlb + (((unsigned)(SRC)) << 8) + boff); \
        MA = (f32x2){__uint_as_float(u << 16),                              \
                     __uint_as_float(u & 0xffff0000u)};                     \
        f32x2 ea = MA + xra;                                                \
        ea = __builtin_elementwise_max(ea, 0.2f * ea);                      \
        f32x2 pp = ea * aa;                                                 \
        P = pp.x + pp.y;                                                    \
        P += __shfl_xor(P, 1);                                              \
        P += __shfl_xor(P, 2);                                              \
        P += __shfl_xor(P, 4);                                              \
    }

__global__ __launch_bounds__(256) void k_gat2(const unsigned short* __restrict__ xl,
                                              const unsigned short* __restrict__ xr,
                                              const float* __restrict__ att,
                                              const float* __restrict__ bias,
                                              const int* __restrict__ rowptr,
                                              const int* __restrict__ col,
                                              float* __restrict__ out) {
    int wv = blockIdx.x * 4 + (threadIdx.x >> 6);
    if (wv >= NN) return;
    int lane = threadIdx.x & 63;
    int c0 = lane * 2;
    const char* xlb = (const char*)xl;
    unsigned boff = (unsigned)c0 * 2;

    ushort2 xrv = *(const ushort2*)(xr + (size_t)wv * 128 + c0);
    f32x2 xra = (f32x2){bf2f(xrv.x), bf2f(xrv.y)};
    float2 a2 = *(const float2*)(att + c0);
    f32x2 aa = (f32x2){a2.x, a2.y};

    f32x2 sa; float pS;
    GAT2_EDGE(wv, sa, pS);
    float mrun = pS, lrun = 1.f;
    f32x2 acca = sa;

    int beg = rowptr[wv], end = rowptr[wv + 1];
    int idx = beg;
    for (; idx + 4 <= end; idx += 4) {
        int s0 = col[idx], s1 = col[idx + 1], s2 = col[idx + 2], s3 = col[idx + 3];
        f32x2 ma0, ma1, ma2, ma3;
        float p0, p1, p2, p3;
        GAT2_EDGE(s0, ma0, p0);
        GAT2_EDGE(s1, ma1, p1);
        GAT2_EDGE(s2, ma2, p2);
        GAT2_EDGE(s3, ma3, p3);
        float nm = fmaxf(fmaxf(fmaxf(p0, p1), fmaxf(p2, p3)), mrun);
        float sc = __expf(mrun - nm);
        float w0 = __expf(p0 - nm), w1 = __expf(p1 - nm);
        float w2 = __expf(p2 - nm), w3 = __expf(p3 - nm);
        acca = acca * sc + ma0 * w0 + ma1 * w1 + ma2 * w2 + ma3 * w3;
        lrun = lrun * sc + w0 + w1 + w2 + w3;
        mrun = nm;
    }
    for (; idx < end; ++idx) {
        int src = col[idx];
        f32x2 ma; float p;
        GAT2_EDGE(src, ma, p);
        float nm = fmaxf(mrun, p);
        float sc = __expf(mrun - nm);
        float w = __expf(p - nm);
        acca = acca * sc + ma * w;
        lrun = lrun * sc + w;
        mrun = nm;
    }

    float inv = 1.f / lrun;
    float ox = acca.x * inv + bias[c0];
    float oy = acca.y * inv + bias[c0 + 1];

    float mx = fmaxf(ox, oy);
    #pragma unroll
    for (int off = 1; off < 64; off <<= 1) mx = fmaxf(mx, __shfl_xor(mx, off));
    float se = __expf(ox - mx) + __expf(oy - mx);
    #pragma unroll
    for (int off = 1; off < 64; off <<= 1) se += __shfl_xor(se, off);
    float lse = mx + logf(se);

    out[(size_t)wv * 128 + c0] = ox - lse;
    out[(size_t)wv * 128 + c0 + 1] = oy - lse;
}

// ---------------- launch ----------------
extern "C" void kernel_launch(void* const* d_in, const int* in_sizes, int n_in,
                              void* d_out, int out_size, void* d_ws, size_t ws_size,
                              hipStream_t stream) {
    const float* x    = (const float*)d_in[0];
    const int*   ei   = (const int*)d_in[1];
    const float* W1l  = (const float*)d_in[2];
    const float* W1r  = (const float*)d_in[3];
    const float* att1 = (const float*)d_in[4];
    const float* b1   = (const float*)d_in[5];
    const float* W2l  = (const float*)d_in[6];
    const float* W2r  = (const float*)d_in[7];
    const float* att2 = (const float*)d_in[8];
    const float* b2   = (const float*)d_in[9];
    float* out = (float*)d_out;

    char* p = (char*)d_ws;
    auto alloc = [&](size_t bytes) {
        char* r = p;
        p += (bytes + 255) & ~(size_t)255;
        return r;
    };
    int* deg      = (int*)alloc((size_t)NN * 4);
    int* rowptr   = (int*)alloc((size_t)(NN + 1) * 4);
    int* bsum     = (int*)alloc((size_t)NB * 4);
    int* cursor   = (int*)alloc((size_t)NN * 4);
    int* col      = (int*)alloc((size_t)NE * 4);
    unsigned short* Wp1  = (unsigned short*)alloc((size_t)65536 * 2);
    unsigned short* Wp2  = (unsigned short*)alloc((size_t)65536 * 2);
    unsigned short* xl1b = (unsigned short*)alloc((size_t)NN * 256 * 2);
    unsigned short* xr1b = (unsigned short*)alloc((size_t)NN * 256 * 2);
    unsigned short* h1b  = (unsigned short*)alloc((size_t)NN * 256 * 2);
    unsigned short* xl2b = (unsigned short*)alloc((size_t)NN * 128 * 2);
    unsigned short* xr2b = (unsigned short*)alloc((size_t)NN * 128 * 2);

    hipMemsetAsync(deg, 0, (size_t)NN * 4, stream);
    int egrid = (NE + 255) / 256;
    k_hist<<<egrid, 256, 0, stream>>>(ei, deg);
    k_scan_block<<<NB, 256, 0, stream>>>(deg, rowptr, bsum);
    k_scan_top<<<1, 256, 0, stream>>>(bsum);
    k_scan_add<<<NB, 256, 0, stream>>>(rowptr, bsum, cursor);
    k_scatter<<<egrid, 256, 0, stream>>>(ei, cursor, col);

    // prep (W only; x converted inside GEMM1 staging)
    k_prep_w<128, 256, 4><<<256, 256, 0, stream>>>(W1l, W1r, Wp1);
    k_prep_w<256, 128, 2><<<256, 256, 0, stream>>>(W2l, W2r, Wp2);

    int rblk = (NN + 63) / 64;  // 782
    k_gemm_mfma<128, 4, true><<<rblk, 256, 0, stream>>>(x, Wp1, xl1b, xr1b, 256);
    k_gat1<<<(NN + 3) / 4, 256, 0, stream>>>(xl1b, xr1b, att1, b1, rowptr, col, h1b);
    k_gemm_mfma<256, 2, false><<<rblk, 256, 0, stream>>>(h1b, Wp2, xl2b, xr2b, 128);
    k_gat2<<<(NN + 3) / 4, 256, 0, stream>>>(xl2b, xr2b, att2, b2, rowptr, col, out);
}

// Round 15
// 310.496 us; speedup vs baseline: 1.9013x; 1.0032x over previous
//
#include <hip/hip_runtime.h>
#include <math.h>

// GATv2 2-layer: N=50000, E=600000, heads=8, C1=32, C2=16.
// CSR build -> prep (W->MFMA-fragment-packed bf16) -> MFMA GEMM1 (fused f32->bf16)
// -> GAT1(+ELU) -> MFMA GEMM2 -> GAT2(+log_softmax).
// GAT: f32x2 packed math, 8-deep edge unroll, DPP quad-perm head reduce.
constexpr int NN = 50000;
constexpr int NE = 600000;
constexpr int NB = (NN + 255) / 256;

typedef __bf16 bf16x8 __attribute__((ext_vector_type(8)));
typedef float f32x4 __attribute__((ext_vector_type(4)));
typedef float f32x2 __attribute__((ext_vector_type(2)));

__device__ inline unsigned short f2bf(float f) {
    unsigned int u = __float_as_uint(f);
    u += 0x7fffu + ((u >> 16) & 1u);   // RNE
    return (unsigned short)(u >> 16);
}
__device__ inline float bf2f(unsigned short s) {
    return __uint_as_float((unsigned int)s << 16);
}
// sum with DPP quad_perm xor partner (VALU pipe, no LDS)
__device__ inline float dpp_add_xor1(float v) {
    int x = __builtin_amdgcn_mov_dpp(__float_as_int(v), 0xB1, 0xf, 0xf, true); // [1,0,3,2]
    return v + __int_as_float(x);
}
__device__ inline float dpp_add_xor2(float v) {
    int x = __builtin_amdgcn_mov_dpp(__float_as_int(v), 0x4E, 0xf, 0xf, true); // [2,3,0,1]
    return v + __int_as_float(x);
}

// ---------------- CSR build ----------------
__global__ __launch_bounds__(256) void k_hist(const int* __restrict__ ei,
                                              int* __restrict__ deg) {
    int e = blockIdx.x * 256 + threadIdx.x;
    if (e < NE) atomicAdd(&deg[ei[NE + e]], 1);
}

__global__ __launch_bounds__(256) void k_scan_block(const int* __restrict__ deg,
                                                    int* __restrict__ rowptr,
                                                    int* __restrict__ bsum) {
    __shared__ int s[256];
    int tid = threadIdx.x;
    int i = blockIdx.x * 256 + tid;
    int v = (i < NN) ? deg[i] : 0;
    s[tid] = v;
    __syncthreads();
    #pragma unroll
    for (int off = 1; off < 256; off <<= 1) {
        int t = (tid >= off) ? s[tid - off] : 0;
        __syncthreads();
        s[tid] += t;
        __syncthreads();
    }
    if (i < NN) rowptr[i] = s[tid] - v;
    if (tid == 255) bsum[blockIdx.x] = s[255];
}

__global__ __launch_bounds__(256) void k_scan_top(int* __restrict__ bsum) {
    __shared__ int s[256];
    int tid = threadIdx.x;
    int v = (tid < NB) ? bsum[tid] : 0;
    s[tid] = v;
    __syncthreads();
    #pragma unroll
    for (int off = 1; off < 256; off <<= 1) {
        int t = (tid >= off) ? s[tid - off] : 0;
        __syncthreads();
        s[tid] += t;
        __syncthreads();
    }
    if (tid < NB) bsum[tid] = s[tid] - v;
}

__global__ __launch_bounds__(256) void k_scan_add(int* __restrict__ rowptr,
                                                  const int* __restrict__ bsum,
                                                  int* __restrict__ cursor) {
    int i = blockIdx.x * 256 + threadIdx.x;
    if (i < NN) {
        int r = rowptr[i] + bsum[blockIdx.x];
        rowptr[i] = r;
        cursor[i] = r;
    }
    if (i == 0) rowptr[NN] = NE;
}

__global__ __launch_bounds__(256) void k_scatter(const int* __restrict__ ei,
                                                 int* __restrict__ cursor,
                                                 int* __restrict__ col) {
    int e = blockIdx.x * 256 + threadIdx.x;
    if (e < NE) {
        int s = ei[e];
        int d = ei[NE + e];
        int p = atomicAdd(&cursor[d], 1);
        col[p] = s;
    }
}

// ---------------- prep ----------------
// Pack W into MFMA-fragment order:
// Wp[ (((t*8+f)*KS+ks)*64 + l)*8 + j ] = B[k=ks*32+(l>>4)*8+j][c=t*128+f*16+(l&15)]
template <int K, int M, int NT>
__global__ __launch_bounds__(256) void k_prep_w(const float* __restrict__ Wl,
                                                const float* __restrict__ Wr,
                                                unsigned short* __restrict__ Wp) {
    constexpr int KS = K / 32;
    int i = blockIdx.x * 256 + threadIdx.x;
    if (i >= NT * 8 * KS * 512) return;
    int idx = i;
    int j = idx & 7; idx >>= 3;
    int l = idx & 63; idx >>= 6;
    int ks = idx % KS; idx /= KS;
    int f = idx & 7; idx >>= 3;
    int t = idx;
    int k = ks * 32 + (l >> 4) * 8 + j;
    int c = t * 128 + f * 16 + (l & 15);
    float v = (c < M) ? Wl[(size_t)k * M + c] : Wr[(size_t)k * M + (c - M)];
    Wp[i] = f2bf(v);
}

// ---------------- MFMA bf16 dual GEMM ----------------
template <int K, int NT, bool CVT>
__global__ __launch_bounds__(256) void k_gemm_mfma(
        const void* __restrict__ Xin,
        const unsigned short* __restrict__ Wp,
        unsigned short* __restrict__ Yl,
        unsigned short* __restrict__ Yr,
        int Mh) {
    constexpr int KS = K / 32;
    constexpr int KP = K + 8;
    __shared__ unsigned short As[64 * KP];

    int tid = threadIdx.x;
    int row0 = blockIdx.x * 64;

    for (int i = tid; i < 64 * K / 4; i += 256) {
        int idx = i * 4;
        int r = idx / K, c = idx - r * K;
        int gr = row0 + r;
        ushort4 v = make_ushort4(0, 0, 0, 0);
        if (gr < NN) {
            if constexpr (CVT) {
                float4 x4 = *(const float4*)((const float*)Xin + (size_t)gr * K + c);
                v = make_ushort4(f2bf(x4.x), f2bf(x4.y), f2bf(x4.z), f2bf(x4.w));
            } else {
                v = *(const ushort4*)((const unsigned short*)Xin + (size_t)gr * K + c);
            }
        }
        *(ushort4*)&As[r * KP + c] = v;
    }
    __syncthreads();

    int wid = tid >> 6, lane = tid & 63;
    int lr = lane & 15, lg = lane >> 4;
    const unsigned short* ap = As + (wid * 16 + lr) * KP + lg * 8;

    bf16x8 a[KS];
    #pragma unroll
    for (int ks = 0; ks < KS; ++ks) a[ks] = *(const bf16x8*)(ap + ks * 32);

    const unsigned short* bbase = Wp + (size_t)lane * 8;

    for (int t = 0; t < NT; ++t) {
        f32x4 acc[8];
        #pragma unroll
        for (int f = 0; f < 8; ++f) acc[f] = (f32x4){0.f, 0.f, 0.f, 0.f};

        #pragma unroll
        for (int f = 0; f < 8; ++f) {
            #pragma unroll
            for (int ks = 0; ks < KS; ++ks) {
                bf16x8 b = *(const bf16x8*)(bbase +
                    ((size_t)((t * 8 + f) * KS + ks) << 9));
                acc[f] = __builtin_amdgcn_mfma_f32_16x16x32_bf16(a[ks], b, acc[f], 0, 0, 0);
            }
        }

        bool isL = (t < NT / 2);
        int cb = (isL ? t : (t - NT / 2)) * 128;
        unsigned short* Y = isL ? Yl : Yr;
        #pragma unroll
        for (int f = 0; f < 8; ++f) {
            #pragma unroll
            for (int r = 0; r < 4; ++r) {
                int row = row0 + wid * 16 + lg * 4 + r;
                if (row < NN) Y[(size_t)row * Mh + cb + f * 16 + lr] = f2bf(acc[f][r]);
            }
        }
    }
}

// ---------------- GAT layer 1: 8-edge unroll, DPP reduce ----------------
// row = 512 B (256 bf16). MA/MB are f32x2 message pairs, P the head logit.
#define GAT1_EDGE(SRC, MA, MB, P)                                           \
    {                                                                       \
        uint2 u = *(const uint2*)(xlb + (((unsigned)(SRC)) << 9) + boff);   \
        MA = (f32x2){__uint_as_float(u.x << 16),                            \
                     __uint_as_float(u.x & 0xffff0000u)};                   \
        MB = (f32x2){__uint_as_float(u.y << 16),                            \
                     __uint_as_float(u.y & 0xffff0000u)};                   \
        f32x2 ea = MA + xra, eb = MB + xrb;                                 \
        ea = __builtin_elementwise_max(ea, 0.2f * ea);                      \
        eb = __builtin_elementwise_max(eb, 0.2f * eb);                      \
        f32x2 pp = ea * aa + eb * ab;                                       \
        P = pp.x + pp.y;                                                    \
        P = dpp_add_xor1(P);                                                \
        P = dpp_add_xor2(P);                                                \
        P += __shfl_xor(P, 4);                                              \
    }

__global__ __launch_bounds__(256) void k_gat1(const unsigned short* __restrict__ xl,
                                              const unsigned short* __restrict__ xr,
                                              const float* __restrict__ att,
                                              const float* __restrict__ bias,
                                              const int* __restrict__ rowptr,
                                              const int* __restrict__ col,
                                              unsigned short* __restrict__ hout) {
    int wv = blockIdx.x * 4 + (threadIdx.x >> 6);
    if (wv >= NN) return;
    int lane = threadIdx.x & 63;
    int c0 = lane * 4;
    const char* xlb = (const char*)xl;
    unsigned boff = (unsigned)c0 * 2;

    ushort4 xrv = *(const ushort4*)(xr + (size_t)wv * 256 + c0);
    f32x2 xra = (f32x2){bf2f(xrv.x), bf2f(xrv.y)};
    f32x2 xrb = (f32x2){bf2f(xrv.z), bf2f(xrv.w)};
    float4 a4 = *(const float4*)(att + c0);
    f32x2 aa = (f32x2){a4.x, a4.y};
    f32x2 ab = (f32x2){a4.z, a4.w};

    // self loop initializes running state
    f32x2 sa, sb; float pS;
    GAT1_EDGE(wv, sa, sb, pS);
    float mrun = pS, lrun = 1.f;
    f32x2 acca = sa, accb = sb;

    int beg = rowptr[wv], end = rowptr[wv + 1];
    int idx = beg;
    for (; idx + 8 <= end; idx += 8) {
        int s0 = col[idx],     s1 = col[idx + 1], s2 = col[idx + 2], s3 = col[idx + 3];
        int s4 = col[idx + 4], s5 = col[idx + 5], s6 = col[idx + 6], s7 = col[idx + 7];
        f32x2 ma0, mb0, ma1, mb1, ma2, mb2, ma3, mb3;
        f32x2 ma4, mb4, ma5, mb5, ma6, mb6, ma7, mb7;
        float p0, p1, p2, p3, p4, p5, p6, p7;
        GAT1_EDGE(s0, ma0, mb0, p0);
        GAT1_EDGE(s1, ma1, mb1, p1);
        GAT1_EDGE(s2, ma2, mb2, p2);
        GAT1_EDGE(s3, ma3, mb3, p3);
        GAT1_EDGE(s4, ma4, mb4, p4);
        GAT1_EDGE(s5, ma5, mb5, p5);
        GAT1_EDGE(s6, ma6, mb6, p6);
        GAT1_EDGE(s7, ma7, mb7, p7);
        float nm = fmaxf(fmaxf(fmaxf(p0, p1), fmaxf(p2, p3)),
                         fmaxf(fmaxf(p4, p5), fmaxf(p6, p7)));
        nm = fmaxf(nm, mrun);
        float sc = __expf(mrun - nm);
        float w0 = __expf(p0 - nm), w1 = __expf(p1 - nm);
        float w2 = __expf(p2 - nm), w3 = __expf(p3 - nm);
        float w4 = __expf(p4 - nm), w5 = __expf(p5 - nm);
        float w6 = __expf(p6 - nm), w7 = __expf(p7 - nm);
        acca = acca * sc + ma0 * w0 + ma1 * w1 + ma2 * w2 + ma3 * w3
                         + ma4 * w4 + ma5 * w5 + ma6 * w6 + ma7 * w7;
        accb = accb * sc + mb0 * w0 + mb1 * w1 + mb2 * w2 + mb3 * w3
                         + mb4 * w4 + mb5 * w5 + mb6 * w6 + mb7 * w7;
        lrun = lrun * sc + w0 + w1 + w2 + w3 + w4 + w5 + w6 + w7;
        mrun = nm;
    }
    for (; idx + 4 <= end; idx += 4) {
        int s0 = col[idx], s1 = col[idx + 1], s2 = col[idx + 2], s3 = col[idx + 3];
        f32x2 ma0, mb0, ma1, mb1, ma2, mb2, ma3, mb3;
        float p0, p1, p2, p3;
        GAT1_EDGE(s0, ma0, mb0, p0);
        GAT1_EDGE(s1, ma1, mb1, p1);
        GAT1_EDGE(s2, ma2, mb2, p2);
        GAT1_EDGE(s3, ma3, mb3, p3);
        float nm = fmaxf(fmaxf(fmaxf(p0, p1), fmaxf(p2, p3)), mrun);
        float sc = __expf(mrun - nm);
        float w0 = __expf(p0 - nm), w1 = __expf(p1 - nm);
        float w2 = __expf(p2 - nm), w3 = __expf(p3 - nm);
        acca = acca * sc + ma0 * w0 + ma1 * w1 + ma2 * w2 + ma3 * w3;
        accb = accb * sc + mb0 * w0 + mb1 * w1 + mb2 * w2 + mb3 * w3;
        lrun = lrun * sc + w0 + w1 + w2 + w3;
        mrun = nm;
    }
    for (; idx < end; ++idx) {
        int src = col[idx];
        f32x2 ma, mb; float p;
        GAT1_EDGE(src, ma, mb, p);
        float nm = fmaxf(mrun, p);
        float sc = __expf(mrun - nm);
        float w = __expf(p - nm);
        acca = acca * sc + ma * w;
        accb = accb * sc + mb * w;
        lrun = lrun * sc + w;
        mrun = nm;
    }

    float inv = 1.f / lrun;
    float4 b4 = *(const float4*)(bias + c0);
    float ox = acca.x * inv + b4.x; ox = ox > 0.f ? ox : (__expf(ox) - 1.f);  // ELU
    float oy = acca.y * inv + b4.y; oy = oy > 0.f ? oy : (__expf(oy) - 1.f);
    float oz = accb.x * inv + b4.z; oz = oz > 0.f ? oz : (__expf(oz) - 1.f);
    float ow = accb.y * inv + b4.w; ow = ow > 0.f ? ow : (__expf(ow) - 1.f);
    *(ushort4*)(hout + (size_t)wv * 256 + c0) =
        make_ushort4(f2bf(ox), f2bf(oy), f2bf(oz), f2bf(ow));
}

// ---------------- GAT layer 2 + log_softmax: 8-edge unroll, DPP reduce -------
// row = 256 B (128 bf16).
#define GAT2_EDGE(SRC, MA, P)                                               \
    {                                                                       \
        unsigned u = *(const unsigned*)(xlb + (((unsigned)(SRC)) << 8) + boff); \
        MA = (f32x2){__uint_as_float(u << 16),                              \
                     __uint_as_float(u & 0xffff0000u)};                     \
        f32x2 ea = MA + xra;                                                \
        ea = __builtin_elementwise_max(ea, 0.2f * ea);                      \
        f32x2 pp = ea * aa;                                                 \
        P = pp.x + pp.y;                                                    \
        P = dpp_add_xor1(P);                                                \
        P = dpp_add_xor2(P);                                                \
        P += __shfl_xor(P, 4);                                              \
    }

__global__ __launch_bounds__(256) void k_gat2(const unsigned short* __restrict__ xl,
                                              const unsigned short* __restrict__ xr,
                                              const float* __restrict__ att,
                                              const float* __restrict__ bias,
                                              const int* __restrict__ rowptr,
                                              const int* __restrict__ col,
                                              float* __restrict__ out) {
    int wv = blockIdx.x * 4 + (threadIdx.x >> 6);
    if (wv >= NN) return;
    int lane = threadIdx.x & 63;
    int c0 = lane * 2;
    const char* xlb = (const char*)xl;
    unsigned boff = (unsigned)c0 * 2;

    ushort2 xrv = *(const ushort2*)(xr + (size_t)wv * 128 + c0);
    f32x2 xra = (f32x2){bf2f(xrv.x), bf2f(xrv.y)};
    float2 a2 = *(const float2*)(att + c0);
    f32x2 aa = (f32x2){a2.x, a2.y};

    f32x2 sa; float pS;
    GAT2_EDGE(wv, sa, pS);
    float mrun = pS, lrun = 1.f;
    f32x2 acca = sa;

    int beg = rowptr[wv], end = rowptr[wv + 1];
    int idx = beg;
    for (; idx + 8 <= end; idx += 8) {
        int s0 = col[idx],     s1 = col[idx + 1], s2 = col[idx + 2], s3 = col[idx + 3];
        int s4 = col[idx + 4], s5 = col[idx + 5], s6 = col[idx + 6], s7 = col[idx + 7];
        f32x2 ma0, ma1, ma2, ma3, ma4, ma5, ma6, ma7;
        float p0, p1, p2, p3, p4, p5, p6, p7;
        GAT2_EDGE(s0, ma0, p0);
        GAT2_EDGE(s1, ma1, p1);
        GAT2_EDGE(s2, ma2, p2);
        GAT2_EDGE(s3, ma3, p3);
        GAT2_EDGE(s4, ma4, p4);
        GAT2_EDGE(s5, ma5, p5);
        GAT2_EDGE(s6, ma6, p6);
        GAT2_EDGE(s7, ma7, p7);
        float nm = fmaxf(fmaxf(fmaxf(p0, p1), fmaxf(p2, p3)),
                         fmaxf(fmaxf(p4, p5), fmaxf(p6, p7)));
        nm = fmaxf(nm, mrun);
        float sc = __expf(mrun - nm);
        float w0 = __expf(p0 - nm), w1 = __expf(p1 - nm);
        float w2 = __expf(p2 - nm), w3 = __expf(p3 - nm);
        float w4 = __expf(p4 - nm), w5 = __expf(p5 - nm);
        float w6 = __expf(p6 - nm), w7 = __expf(p7 - nm);
        acca = acca * sc + ma0 * w0 + ma1 * w1 + ma2 * w2 + ma3 * w3
                         + ma4 * w4 + ma5 * w5 + ma6 * w6 + ma7 * w7;
        lrun = lrun * sc + w0 + w1 + w2 + w3 + w4 + w5 + w6 + w7;
        mrun = nm;
    }
    for (; idx + 4 <= end; idx += 4) {
        int s0 = col[idx], s1 = col[idx + 1], s2 = col[idx + 2], s3 = col[idx + 3];
        f32x2 ma0, ma1, ma2, ma3;
        float p0, p1, p2, p3;
        GAT2_EDGE(s0, ma0, p0);
        GAT2_EDGE(s1, ma1, p1);
        GAT2_EDGE(s2, ma2, p2);
        GAT2_EDGE(s3, ma3, p3);
        float nm = fmaxf(fmaxf(fmaxf(p0, p1), fmaxf(p2, p3)), mrun);
        float sc = __expf(mrun - nm);
        float w0 = __expf(p0 - nm), w1 = __expf(p1 - nm);
        float w2 = __expf(p2 - nm), w3 = __expf(p3 - nm);
        acca = acca * sc + ma0 * w0 + ma1 * w1 + ma2 * w2 + ma3 * w3;
        lrun = lrun * sc + w0 + w1 + w2 + w3;
        mrun = nm;
    }
    for (; idx < end; ++idx) {
        int src = col[idx];
        f32x2 ma; float p;
        GAT2_EDGE(src, ma, p);
        float nm = fmaxf(mrun, p);
        float sc = __expf(mrun - nm);
        float w = __expf(p - nm);
        acca = acca * sc + ma * w;
        lrun = lrun * sc + w;
        mrun = nm;
    }

    float inv = 1.f / lrun;
    float ox = acca.x * inv + bias[c0];
    float oy = acca.y * inv + bias[c0 + 1];

    float mx = fmaxf(ox, oy);
    #pragma unroll
    for (int off = 1; off < 64; off <<= 1) mx = fmaxf(mx, __shfl_xor(mx, off));
    float se = __expf(ox - mx) + __expf(oy - mx);
    #pragma unroll
    for (int off = 1; off < 64; off <<= 1) se += __shfl_xor(se, off);
    float lse = mx + logf(se);

    out[(size_t)wv * 128 + c0] = ox - lse;
    out[(size_t)wv * 128 + c0 + 1] = oy - lse;
}

// ---------------- launch ----------------
extern "C" void kernel_launch(void* const* d_in, const int* in_sizes, int n_in,
                              void* d_out, int out_size, void* d_ws, size_t ws_size,
                              hipStream_t stream) {
    const float* x    = (const float*)d_in[0];
    const int*   ei   = (const int*)d_in[1];
    const float* W1l  = (const float*)d_in[2];
    const float* W1r  = (const float*)d_in[3];
    const float* att1 = (const float*)d_in[4];
    const float* b1   = (const float*)d_in[5];
    const float* W2l  = (const float*)d_in[6];
    const float* W2r  = (const float*)d_in[7];
    const float* att2 = (const float*)d_in[8];
    const float* b2   = (const float*)d_in[9];
    float* out = (float*)d_out;

    char* p = (char*)d_ws;
    auto alloc = [&](size_t bytes) {
        char* r = p;
        p += (bytes + 255) & ~(size_t)255;
        return r;
    };
    int* deg      = (int*)alloc((size_t)NN * 4);
    int* rowptr   = (int*)alloc((size_t)(NN + 1) * 4);
    int* bsum     = (int*)alloc((size_t)NB * 4);
    int* cursor   = (int*)alloc((size_t)NN * 4);
    int* col      = (int*)alloc((size_t)NE * 4);
    unsigned short* Wp1  = (unsigned short*)alloc((size_t)65536 * 2);
    unsigned short* Wp2  = (unsigned short*)alloc((size_t)65536 * 2);
    unsigned short* xl1b = (unsigned short*)alloc((size_t)NN * 256 * 2);
    unsigned short* xr1b = (unsigned short*)alloc((size_t)NN * 256 * 2);
    unsigned short* h1b  = (unsigned short*)alloc((size_t)NN * 256 * 2);
    unsigned short* xl2b = (unsigned short*)alloc((size_t)NN * 128 * 2);
    unsigned short* xr2b = (unsigned short*)alloc((size_t)NN * 128 * 2);

    hipMemsetAsync(deg, 0, (size_t)NN * 4, stream);
    int egrid = (NE + 255) / 256;
    k_hist<<<egrid, 256, 0, stream>>>(ei, deg);
    k_scan_block<<<NB, 256, 0, stream>>>(deg, rowptr, bsum);
    k_scan_top<<<1, 256, 0, stream>>>(bsum);
    k_scan_add<<<NB, 256, 0, stream>>>(rowptr, bsum, cursor);
    k_scatter<<<egrid, 256, 0, stream>>>(ei, cursor, col);

    // prep (W only; x converted inside GEMM1 staging)
    k_prep_w<128, 256, 4><<<256, 256, 0, stream>>>(W1l, W1r, Wp1);
    k_prep_w<256, 128, 2><<<256, 256, 0, stream>>>(W2l, W2r, Wp2);

    int rblk = (NN + 63) / 64;  // 782
    k_gemm_mfma<128, 4, true><<<rblk, 256, 0, stream>>>(x, Wp1, xl1b, xr1b, 256);
    k_gat1<<<(NN + 3) / 4, 256, 0, stream>>>(xl1b, xr1b, att1, b1, rowptr, col, h1b);
    k_gemm_mfma<256, 2, false><<<rblk, 256, 0, stream>>>(h1b, Wp2, xl2b, xr2b, 128);
    k_gat2<<<(NN + 3) / 4, 256, 0, stream>>>(xl2b, xr2b, att2, b2, rowptr, col, out);
}

// Round 16
// 307.611 us; speedup vs baseline: 1.9191x; 1.0094x over previous
//
#include <hip/hip_runtime.h>
#include <math.h>

// GATv2 2-layer: N=50000, E=600000, heads=8, C1=32, C2=16.
// CSR build -> prep (W->MFMA-fragment-packed bf16) -> MFMA GEMM1 (fused f32->bf16)
// -> GAT1(+ELU) -> MFMA GEMM2 -> GAT2(+log_softmax).
// GAT: f32x2 packed math, 4-edge unroll (32 VGPR / high occupancy),
// DPP quad-perm head reduce (VALU pipe) + single shfl_xor(4).
constexpr int NN = 50000;
constexpr int NE = 600000;
constexpr int NB = (NN + 255) / 256;

typedef __bf16 bf16x8 __attribute__((ext_vector_type(8)));
typedef float f32x4 __attribute__((ext_vector_type(4)));
typedef float f32x2 __attribute__((ext_vector_type(2)));

__device__ inline unsigned short f2bf(float f) {
    unsigned int u = __float_as_uint(f);
    u += 0x7fffu + ((u >> 16) & 1u);   // RNE
    return (unsigned short)(u >> 16);
}
__device__ inline float bf2f(unsigned short s) {
    return __uint_as_float((unsigned int)s << 16);
}
// sum with DPP quad_perm xor partner (VALU pipe, no LDS)
__device__ inline float dpp_add_xor1(float v) {
    int x = __builtin_amdgcn_mov_dpp(__float_as_int(v), 0xB1, 0xf, 0xf, true); // [1,0,3,2]
    return v + __int_as_float(x);
}
__device__ inline float dpp_add_xor2(float v) {
    int x = __builtin_amdgcn_mov_dpp(__float_as_int(v), 0x4E, 0xf, 0xf, true); // [2,3,0,1]
    return v + __int_as_float(x);
}

// ---------------- CSR build ----------------
__global__ __launch_bounds__(256) void k_hist(const int* __restrict__ ei,
                                              int* __restrict__ deg) {
    int e = blockIdx.x * 256 + threadIdx.x;
    if (e < NE) atomicAdd(&deg[ei[NE + e]], 1);
}

__global__ __launch_bounds__(256) void k_scan_block(const int* __restrict__ deg,
                                                    int* __restrict__ rowptr,
                                                    int* __restrict__ bsum) {
    __shared__ int s[256];
    int tid = threadIdx.x;
    int i = blockIdx.x * 256 + tid;
    int v = (i < NN) ? deg[i] : 0;
    s[tid] = v;
    __syncthreads();
    #pragma unroll
    for (int off = 1; off < 256; off <<= 1) {
        int t = (tid >= off) ? s[tid - off] : 0;
        __syncthreads();
        s[tid] += t;
        __syncthreads();
    }
    if (i < NN) rowptr[i] = s[tid] - v;
    if (tid == 255) bsum[blockIdx.x] = s[255];
}

__global__ __launch_bounds__(256) void k_scan_top(int* __restrict__ bsum) {
    __shared__ int s[256];
    int tid = threadIdx.x;
    int v = (tid < NB) ? bsum[tid] : 0;
    s[tid] = v;
    __syncthreads();
    #pragma unroll
    for (int off = 1; off < 256; off <<= 1) {
        int t = (tid >= off) ? s[tid - off] : 0;
        __syncthreads();
        s[tid] += t;
        __syncthreads();
    }
    if (tid < NB) bsum[tid] = s[tid] - v;
}

__global__ __launch_bounds__(256) void k_scan_add(int* __restrict__ rowptr,
                                                  const int* __restrict__ bsum,
                                                  int* __restrict__ cursor) {
    int i = blockIdx.x * 256 + threadIdx.x;
    if (i < NN) {
        int r = rowptr[i] + bsum[blockIdx.x];
        rowptr[i] = r;
        cursor[i] = r;
    }
    if (i == 0) rowptr[NN] = NE;
}

__global__ __launch_bounds__(256) void k_scatter(const int* __restrict__ ei,
                                                 int* __restrict__ cursor,
                                                 int* __restrict__ col) {
    int e = blockIdx.x * 256 + threadIdx.x;
    if (e < NE) {
        int s = ei[e];
        int d = ei[NE + e];
        int p = atomicAdd(&cursor[d], 1);
        col[p] = s;
    }
}

// ---------------- prep ----------------
// Pack W into MFMA-fragment order:
// Wp[ (((t*8+f)*KS+ks)*64 + l)*8 + j ] = B[k=ks*32+(l>>4)*8+j][c=t*128+f*16+(l&15)]
template <int K, int M, int NT>
__global__ __launch_bounds__(256) void k_prep_w(const float* __restrict__ Wl,
                                                const float* __restrict__ Wr,
                                                unsigned short* __restrict__ Wp) {
    constexpr int KS = K / 32;
    int i = blockIdx.x * 256 + threadIdx.x;
    if (i >= NT * 8 * KS * 512) return;
    int idx = i;
    int j = idx & 7; idx >>= 3;
    int l = idx & 63; idx >>= 6;
    int ks = idx % KS; idx /= KS;
    int f = idx & 7; idx >>= 3;
    int t = idx;
    int k = ks * 32 + (l >> 4) * 8 + j;
    int c = t * 128 + f * 16 + (l & 15);
    float v = (c < M) ? Wl[(size_t)k * M + c] : Wr[(size_t)k * M + (c - M)];
    Wp[i] = f2bf(v);
}

// ---------------- MFMA bf16 dual GEMM ----------------
template <int K, int NT, bool CVT>
__global__ __launch_bounds__(256) void k_gemm_mfma(
        const void* __restrict__ Xin,
        const unsigned short* __restrict__ Wp,
        unsigned short* __restrict__ Yl,
        unsigned short* __restrict__ Yr,
        int Mh) {
    constexpr int KS = K / 32;
    constexpr int KP = K + 8;
    __shared__ unsigned short As[64 * KP];

    int tid = threadIdx.x;
    int row0 = blockIdx.x * 64;

    for (int i = tid; i < 64 * K / 4; i += 256) {
        int idx = i * 4;
        int r = idx / K, c = idx - r * K;
        int gr = row0 + r;
        ushort4 v = make_ushort4(0, 0, 0, 0);
        if (gr < NN) {
            if constexpr (CVT) {
                float4 x4 = *(const float4*)((const float*)Xin + (size_t)gr * K + c);
                v = make_ushort4(f2bf(x4.x), f2bf(x4.y), f2bf(x4.z), f2bf(x4.w));
            } else {
                v = *(const ushort4*)((const unsigned short*)Xin + (size_t)gr * K + c);
            }
        }
        *(ushort4*)&As[r * KP + c] = v;
    }
    __syncthreads();

    int wid = tid >> 6, lane = tid & 63;
    int lr = lane & 15, lg = lane >> 4;
    const unsigned short* ap = As + (wid * 16 + lr) * KP + lg * 8;

    bf16x8 a[KS];
    #pragma unroll
    for (int ks = 0; ks < KS; ++ks) a[ks] = *(const bf16x8*)(ap + ks * 32);

    const unsigned short* bbase = Wp + (size_t)lane * 8;

    for (int t = 0; t < NT; ++t) {
        f32x4 acc[8];
        #pragma unroll
        for (int f = 0; f < 8; ++f) acc[f] = (f32x4){0.f, 0.f, 0.f, 0.f};

        #pragma unroll
        for (int f = 0; f < 8; ++f) {
            #pragma unroll
            for (int ks = 0; ks < KS; ++ks) {
                bf16x8 b = *(const bf16x8*)(bbase +
                    ((size_t)((t * 8 + f) * KS + ks) << 9));
                acc[f] = __builtin_amdgcn_mfma_f32_16x16x32_bf16(a[ks], b, acc[f], 0, 0, 0);
            }
        }

        bool isL = (t < NT / 2);
        int cb = (isL ? t : (t - NT / 2)) * 128;
        unsigned short* Y = isL ? Yl : Yr;
        #pragma unroll
        for (int f = 0; f < 8; ++f) {
            #pragma unroll
            for (int r = 0; r < 4; ++r) {
                int row = row0 + wid * 16 + lg * 4 + r;
                if (row < NN) Y[(size_t)row * Mh + cb + f * 16 + lr] = f2bf(acc[f][r]);
            }
        }
    }
}

// ---------------- GAT layer 1: 4-edge unroll, f32x2 packed, DPP reduce -------
// row = 512 B (256 bf16). MA/MB are f32x2 message pairs, P the head logit.
#define GAT1_EDGE(SRC, MA, MB, P)                                           \
    {                                                                       \
        uint2 u = *(const uint2*)(xlb + (((unsigned)(SRC)) << 9) + boff);   \
        MA = (f32x2){__uint_as_float(u.x << 16),                            \
                     __uint_as_float(u.x & 0xffff0000u)};                   \
        MB = (f32x2){__uint_as_float(u.y << 16),                            \
                     __uint_as_float(u.y & 0xffff0000u)};                   \
        f32x2 ea = MA + xra, eb = MB + xrb;                                 \
        ea = __builtin_elementwise_max(ea, 0.2f * ea);                      \
        eb = __builtin_elementwise_max(eb, 0.2f * eb);                      \
        f32x2 pp = ea * aa + eb * ab;                                       \
        P = pp.x + pp.y;                                                    \
        P = dpp_add_xor1(P);                                                \
        P = dpp_add_xor2(P);                                                \
        P += __shfl_xor(P, 4);                                              \
    }

__global__ __launch_bounds__(256) void k_gat1(const unsigned short* __restrict__ xl,
                                              const unsigned short* __restrict__ xr,
                                              const float* __restrict__ att,
                                              const float* __restrict__ bias,
                                              const int* __restrict__ rowptr,
                                              const int* __restrict__ col,
                                              unsigned short* __restrict__ hout) {
    int wv = blockIdx.x * 4 + (threadIdx.x >> 6);
    if (wv >= NN) return;
    int lane = threadIdx.x & 63;
    int c0 = lane * 4;
    const char* xlb = (const char*)xl;
    unsigned boff = (unsigned)c0 * 2;

    ushort4 xrv = *(const ushort4*)(xr + (size_t)wv * 256 + c0);
    f32x2 xra = (f32x2){bf2f(xrv.x), bf2f(xrv.y)};
    f32x2 xrb = (f32x2){bf2f(xrv.z), bf2f(xrv.w)};
    float4 a4 = *(const float4*)(att + c0);
    f32x2 aa = (f32x2){a4.x, a4.y};
    f32x2 ab = (f32x2){a4.z, a4.w};

    // self loop initializes running state
    f32x2 sa, sb; float pS;
    GAT1_EDGE(wv, sa, sb, pS);
    float mrun = pS, lrun = 1.f;
    f32x2 acca = sa, accb = sb;

    int beg = rowptr[wv], end = rowptr[wv + 1];
    int idx = beg;
    for (; idx + 4 <= end; idx += 4) {
        int s0 = col[idx], s1 = col[idx + 1], s2 = col[idx + 2], s3 = col[idx + 3];
        f32x2 ma0, mb0, ma1, mb1, ma2, mb2, ma3, mb3;
        float p0, p1, p2, p3;
        GAT1_EDGE(s0, ma0, mb0, p0);
        GAT1_EDGE(s1, ma1, mb1, p1);
        GAT1_EDGE(s2, ma2, mb2, p2);
        GAT1_EDGE(s3, ma3, mb3, p3);
        float nm = fmaxf(fmaxf(fmaxf(p0, p1), fmaxf(p2, p3)), mrun);
        float sc = __expf(mrun - nm);
        float w0 = __expf(p0 - nm), w1 = __expf(p1 - nm);
        float w2 = __expf(p2 - nm), w3 = __expf(p3 - nm);
        acca = acca * sc + ma0 * w0 + ma1 * w1 + ma2 * w2 + ma3 * w3;
        accb = accb * sc + mb0 * w0 + mb1 * w1 + mb2 * w2 + mb3 * w3;
        lrun = lrun * sc + w0 + w1 + w2 + w3;
        mrun = nm;
    }
    for (; idx < end; ++idx) {
        int src = col[idx];
        f32x2 ma, mb; float p;
        GAT1_EDGE(src, ma, mb, p);
        float nm = fmaxf(mrun, p);
        float sc = __expf(mrun - nm);
        float w = __expf(p - nm);
        acca = acca * sc + ma * w;
        accb = accb * sc + mb * w;
        lrun = lrun * sc + w;
        mrun = nm;
    }

    float inv = 1.f / lrun;
    float4 b4 = *(const float4*)(bias + c0);
    float ox = acca.x * inv + b4.x; ox = ox > 0.f ? ox : (__expf(ox) - 1.f);  // ELU
    float oy = acca.y * inv + b4.y; oy = oy > 0.f ? oy : (__expf(oy) - 1.f);
    float oz = accb.x * inv + b4.z; oz = oz > 0.f ? oz : (__expf(oz) - 1.f);
    float ow = accb.y * inv + b4.w; ow = ow > 0.f ? ow : (__expf(ow) - 1.f);
    *(ushort4*)(hout + (size_t)wv * 256 + c0) =
        make_ushort4(f2bf(ox), f2bf(oy), f2bf(oz), f2bf(ow));
}

// ---------------- GAT layer 2 + log_softmax: 4-edge unroll, DPP reduce -------
// row = 256 B (128 bf16).
#define GAT2_EDGE(SRC, MA, P)                                               \
    {                                                                       \
        unsigned u = *(const unsigned*)(xlb + (((unsigned)(SRC)) << 8) + boff); \
        MA = (f32x2){__uint_as_float(u << 16),                              \
                     __uint_as_float(u & 0xffff0000u)};                     \
        f32x2 ea = MA + xra;                                                \
        ea = __builtin_elementwise_max(ea, 0.2f * ea);                      \
        f32x2 pp = ea * aa;                                                 \
        P = pp.x + pp.y;                                                    \
        P = dpp_add_xor1(P);                                                \
        P = dpp_add_xor2(P);                                                \
        P += __shfl_xor(P, 4);                                              \
    }

__global__ __launch_bounds__(256) void k_gat2(const unsigned short* __restrict__ xl,
                                              const unsigned short* __restrict__ xr,
                                              const float* __restrict__ att,
                                              const float* __restrict__ bias,
                                              const int* __restrict__ rowptr,
                                              const int* __restrict__ col,
                                              float* __restrict__ out) {
    int wv = blockIdx.x * 4 + (threadIdx.x >> 6);
    if (wv >= NN) return;
    int lane = threadIdx.x & 63;
    int c0 = lane * 2;
    const char* xlb = (const char*)xl;
    unsigned boff = (unsigned)c0 * 2;

    ushort2 xrv = *(const ushort2*)(xr + (size_t)wv * 128 + c0);
    f32x2 xra = (f32x2){bf2f(xrv.x), bf2f(xrv.y)};
    float2 a2 = *(const float2*)(att + c0);
    f32x2 aa = (f32x2){a2.x, a2.y};

    f32x2 sa; float pS;
    GAT2_EDGE(wv, sa, pS);
    float mrun = pS, lrun = 1.f;
    f32x2 acca = sa;

    int beg = rowptr[wv], end = rowptr[wv + 1];
    int idx = beg;
    for (; idx + 4 <= end; idx += 4) {
        int s0 = col[idx], s1 = col[idx + 1], s2 = col[idx + 2], s3 = col[idx + 3];
        f32x2 ma0, ma1, ma2, ma3;
        float p0, p1, p2, p3;
        GAT2_EDGE(s0, ma0, p0);
        GAT2_EDGE(s1, ma1, p1);
        GAT2_EDGE(s2, ma2, p2);
        GAT2_EDGE(s3, ma3, p3);
        float nm = fmaxf(fmaxf(fmaxf(p0, p1), fmaxf(p2, p3)), mrun);
        float sc = __expf(mrun - nm);
        float w0 = __expf(p0 - nm), w1 = __expf(p1 - nm);
        float w2 = __expf(p2 - nm), w3 = __expf(p3 - nm);
        acca = acca * sc + ma0 * w0 + ma1 * w1 + ma2 * w2 + ma3 * w3;
        lrun = lrun * sc + w0 + w1 + w2 + w3;
        mrun = nm;
    }
    for (; idx < end; ++idx) {
        int src = col[idx];
        f32x2 ma; float p;
        GAT2_EDGE(src, ma, p);
        float nm = fmaxf(mrun, p);
        float sc = __expf(mrun - nm);
        float w = __expf(p - nm);
        acca = acca * sc + ma * w;
        lrun = lrun * sc + w;
        mrun = nm;
    }

    float inv = 1.f / lrun;
    float ox = acca.x * inv + bias[c0];
    float oy = acca.y * inv + bias[c0 + 1];

    float mx = fmaxf(ox, oy);
    #pragma unroll
    for (int off = 1; off < 64; off <<= 1) mx = fmaxf(mx, __shfl_xor(mx, off));
    float se = __expf(ox - mx) + __expf(oy - mx);
    #pragma unroll
    for (int off = 1; off < 64; off <<= 1) se += __shfl_xor(se, off);
    float lse = mx + logf(se);

    out[(size_t)wv * 128 + c0] = ox - lse;
    out[(size_t)wv * 128 + c0 + 1] = oy - lse;
}

// ---------------- launch ----------------
extern "C" void kernel_launch(void* const* d_in, const int* in_sizes, int n_in,
                              void* d_out, int out_size, void* d_ws, size_t ws_size,
                              hipStream_t stream) {
    const float* x    = (const float*)d_in[0];
    const int*   ei   = (const int*)d_in[1];
    const float* W1l  = (const float*)d_in[2];
    const float* W1r  = (const float*)d_in[3];
    const float* att1 = (const float*)d_in[4];
    const float* b1   = (const float*)d_in[5];
    const float* W2l  = (const float*)d_in[6];
    const float* W2r  = (const float*)d_in[7];
    const float* att2 = (const float*)d_in[8];
    const float* b2   = (const float*)d_in[9];
    float* out = (float*)d_out;

    char* p = (char*)d_ws;
    auto alloc = [&](size_t bytes) {
        char* r = p;
        p += (bytes + 255) & ~(size_t)255;
        return r;
    };
    int* deg      = (int*)alloc((size_t)NN * 4);
    int* rowptr   = (int*)alloc((size_t)(NN + 1) * 4);
    int* bsum     = (int*)alloc((size_t)NB * 4);
    int* cursor   = (int*)alloc((size_t)NN * 4);
    int* col      = (int*)alloc((size_t)NE * 4);
    unsigned short* Wp1  = (unsigned short*)alloc((size_t)65536 * 2);
    unsigned short* Wp2  = (unsigned short*)alloc((size_t)65536 * 2);
    unsigned short* xl1b = (unsigned short*)alloc((size_t)NN * 256 * 2);
    unsigned short* xr1b = (unsigned short*)alloc((size_t)NN * 256 * 2);
    unsigned short* h1b  = (unsigned short*)alloc((size_t)NN * 256 * 2);
    unsigned short* xl2b = (unsigned short*)alloc((size_t)NN * 128 * 2);
    unsigned short* xr2b = (unsigned short*)alloc((size_t)NN * 128 * 2);

    hipMemsetAsync(deg, 0, (size_t)NN * 4, stream);
    int egrid = (NE + 255) / 256;
    k_hist<<<egrid, 256, 0, stream>>>(ei, deg);
    k_scan_block<<<NB, 256, 0, stream>>>(deg, rowptr, bsum);
    k_scan_top<<<1, 256, 0, stream>>>(bsum);
    k_scan_add<<<NB, 256, 0, stream>>>(rowptr, bsum, cursor);
    k_scatter<<<egrid, 256, 0, stream>>>(ei, cursor, col);

    // prep (W only; x converted inside GEMM1 staging)
    k_prep_w<128, 256, 4><<<256, 256, 0, stream>>>(W1l, W1r, Wp1);
    k_prep_w<256, 128, 2><<<256, 256, 0, stream>>>(W2l, W2r, Wp2);

    int rblk = (NN + 63) / 64;  // 782
    k_gemm_mfma<128, 4, true><<<rblk, 256, 0, stream>>>(x, Wp1, xl1b, xr1b, 256);
    k_gat1<<<(NN + 3) / 4, 256, 0, stream>>>(xl1b, xr1b, att1, b1, rowptr, col, h1b);
    k_gemm_mfma<256, 2, false><<<rblk, 256, 0, stream>>>(h1b, Wp2, xl2b, xr2b, 128);
    k_gat2<<<(NN + 3) / 4, 256, 0, stream>>>(xl2b, xr2b, att2, b2, rowptr, col, out);
}